// Round 1
// baseline (1011.407 us; speedup 1.0000x reference)
//
#include <hip/hip_runtime.h>

#define NPTS 65536
#define LOGN 16
#define KNB 16
#define NEGS 0.2f
#define EPSV 1e-5f

// GN stages
#define ST_MLP1 0
#define ST_SKIP 1
#define ST_L1   2
#define ST_M1   3
#define ST_L2   4
#define ST_M2   5
#define ST_OUT  6

// ws layout in floats: stats | packed xyz | pre1 | pre_m1 | pre_m2
#define STAT_F 1792                         // 7 stages * 4b * 4g * (2*8 slots)
#define XYZP_OFF 2048
#define PRE1_OFF  (XYZP_OFF + 4*NPTS*4)
#define PREM1_OFF (PRE1_OFF + 4*NPTS*8)
#define PREM2_OFF (PREM1_OFF + 4*NPTS*8)
// total = PREM2_OFF + 4*NPTS*16 = 9,439,232 floats (~36 MB)

__device__ __forceinline__ float lrelu(float v){ return v >= 0.f ? v : v*NEGS; }

__device__ __forceinline__ void stat_fin(const float* st, int stage, int b, int g,
                                         float cnt, float& mean, float& inv){
  const float* p = st + ((stage*4+b)*4+g)*16;
  float s=0.f,q=0.f;
  #pragma unroll
  for(int i=0;i<8;i++){ s += p[i]; q += p[8+i]; }
  mean = s/cnt;
  float var = q/cnt - mean*mean;
  inv = rsqrtf(var + EPSV);
}

__device__ __forceinline__ float wred(float v){
  #pragma unroll
  for(int off=32; off>0; off>>=1) v += __shfl_xor(v, off, 64);
  return v;
}

// ---------------- K0: pack xyz -> float4 [b][n] ----------------
__global__ __launch_bounds__(256) void k_pack(const float* __restrict__ xyz,
                                              float* __restrict__ ws){
  int p = blockIdx.x*256 + threadIdx.x;
  int b = p >> LOGN, n = p & (NPTS-1);
  const float* xb = xyz + b*3*NPTS + n;
  float4 v = make_float4(xb[0], xb[NPTS], xb[2*NPTS], 0.f);
  ((float4*)(ws + XYZP_OFF))[p] = v;
}

// ---------------- K1: mlp1 pre + stats; skip stats; lfa1 stats ----------------
__global__ __launch_bounds__(256) void k1(
    const float* __restrict__ feat, const int* __restrict__ nidx,
    const float* __restrict__ W1,  const float* __restrict__ b1,
    const float* __restrict__ Ws,  const float* __restrict__ bs,
    const float* __restrict__ WL1, const float* __restrict__ bl1,
    float* __restrict__ ws){
  int b = blockIdx.y;
  int n = blockIdx.x*256 + threadIdx.x;
  int p = (b<<LOGN) | n;
  float f[8];
  #pragma unroll
  for(int c=0;c<8;c++) f[c] = feat[(b*8+c)*NPTS + n];
  float* pre1 = ws + PRE1_OFF;

  float s1s[4]={0,0,0,0}, s1q[4]={0,0,0,0};
  #pragma unroll
  for(int c=0;c<8;c++){
    float v = b1[c];
    #pragma unroll
    for(int j=0;j<8;j++) v += W1[c*8+j]*f[j];
    pre1[p*8+c] = v;
    s1s[c>>1]+=v; s1q[c>>1]+=v*v;
  }
  float sss[4]={0,0,0,0}, ssq[4]={0,0,0,0};
  #pragma unroll
  for(int o=0;o<32;o++){
    float v = bs[o];
    #pragma unroll
    for(int j=0;j<8;j++) v += Ws[o*8+j]*f[j];
    sss[o>>3]+=v; ssq[o>>3]+=v*v;
  }
  const float4* xp = (const float4*)(ws + XYZP_OFF);
  float4 ct = xp[p];
  float l1s[4]={0,0,0,0}, l1q[4]={0,0,0,0};
  const int* nr = nidx + p*KNB;
  #pragma unroll
  for(int k=0;k<KNB;k++){
    int idx = nr[k];
    float4 nb = xp[(b<<LOGN)|idx];
    float rx=nb.x-ct.x, ry=nb.y-ct.y, rz=nb.z-ct.z;
    float dd = sqrtf(rx*rx+ry*ry+rz*rz);
    float fr[10] = {dd,rx,ry,rz,ct.x,ct.y,ct.z,nb.x,nb.y,nb.z};
    #pragma unroll
    for(int c=0;c<8;c++){
      float v = bl1[c];
      #pragma unroll
      for(int j=0;j<10;j++) v += WL1[c*10+j]*fr[j];
      l1s[c>>1]+=v; l1q[c>>1]+=v*v;
    }
  }
  __shared__ float lst[24];
  if(threadIdx.x < 24) lst[threadIdx.x] = 0.f;
  __syncthreads();
  int lane = threadIdx.x & 63;
  #pragma unroll
  for(int g=0; g<4; g++){
    float a1v = wred(s1s[g]), a2v = wred(s1q[g]);
    float d1v = wred(sss[g]), d2v = wred(ssq[g]);
    float e1v = wred(l1s[g]), e2v = wred(l1q[g]);
    if(lane==0){
      atomicAdd(&lst[ 0+g*2], a1v); atomicAdd(&lst[ 1+g*2], a2v);
      atomicAdd(&lst[ 8+g*2], d1v); atomicAdd(&lst[ 9+g*2], d2v);
      atomicAdd(&lst[16+g*2], e1v); atomicAdd(&lst[17+g*2], e2v);
    }
  }
  __syncthreads();
  if(threadIdx.x < 24){
    int stage = threadIdx.x >> 3;          // 0=MLP1,1=SKIP,2=L1 (matches enum)
    int g = (threadIdx.x >> 1) & 3;
    int w = threadIdx.x & 1;
    atomicAdd(ws + ((stage*4+b)*4+g)*16 + w*8 + (blockIdx.x&7), lst[threadIdx.x]);
  }
}

// ---------------- K2: att-pool 1 (+ lfa2 stats, m1 pre+stats) ----------------
__global__ __launch_bounds__(256) void k2(
    const int* __restrict__ nidx,
    const float* __restrict__ WL1, const float* __restrict__ bl1,
    const float* __restrict__ gL1, const float* __restrict__ beL1,
    const float* __restrict__ g1,  const float* __restrict__ be1,
    const float* __restrict__ Wa1,
    const float* __restrict__ Wm1, const float* __restrict__ bm1,
    const float* __restrict__ W2,  const float* __restrict__ b2,
    float* __restrict__ ws){
  int b = blockIdx.y;
  int l = threadIdx.x & 15;
  int pg = threadIdx.x >> 4;
  float scP[8], shP[8], scL[8], shL[8];
  #pragma unroll
  for(int g=0; g<4; g++){
    float m, inv;
    stat_fin(ws, ST_MLP1, b, g, 2.0f*NPTS, m, inv);
    #pragma unroll
    for(int u=0;u<2;u++){ int c=g*2+u; scP[c]=inv*g1[c]; shP[c]=be1[c]-m*inv*g1[c]; }
    stat_fin(ws, ST_L1, b, g, 2.0f*NPTS*KNB, m, inv);
    #pragma unroll
    for(int u=0;u<2;u++){ int c=g*2+u; scL[c]=inv*gL1[c]; shL[c]=beL1[c]-m*inv*gL1[c]; }
  }
  const float4* xp = (const float4*)(ws + XYZP_OFF);
  const float* pre1 = ws + PRE1_OFF;
  float* prem1 = ws + PREM1_OFF;

  __shared__ float xs[16][272];
  __shared__ float ssc[16][272];
  __shared__ float aggv[16][16];
  __shared__ float lst[16];
  if(threadIdx.x<16) lst[threadIdx.x]=0.f;

  float l2s[4]={0,0,0,0}, l2q[4]={0,0,0,0};
  float m1s=0.f, m1q=0.f;

  for(int n0 = blockIdx.x*16 + pg; n0 < NPTS; n0 += gridDim.x*16){
    int p = (b<<LOGN) | n0;
    int idx = nidx[p*KNB + l];
    int pi = (b<<LOGN) | idx;
    float4 nb = xp[pi];
    float4 ct = xp[p];
    float rx=nb.x-ct.x, ry=nb.y-ct.y, rz=nb.z-ct.z;
    float dd = sqrtf(rx*rx+ry*ry+rz*rz);
    float fr[10] = {dd,rx,ry,rz,ct.x,ct.y,ct.z,nb.x,nb.y,nb.z};
    float fx[8];
    #pragma unroll
    for(int c=0;c<8;c++){
      float v = bl1[c];
      #pragma unroll
      for(int j=0;j<10;j++) v += WL1[c*10+j]*fr[j];
      fx[c] = lrelu(v*scL[c] + shL[c]);
    }
    float xn[8];
    const float4* pr = (const float4*)(pre1 + pi*8);
    float4 a0 = pr[0], a1 = pr[1];
    xn[0]=lrelu(a0.x*scP[0]+shP[0]); xn[1]=lrelu(a0.y*scP[1]+shP[1]);
    xn[2]=lrelu(a0.z*scP[2]+shP[2]); xn[3]=lrelu(a0.w*scP[3]+shP[3]);
    xn[4]=lrelu(a1.x*scP[4]+shP[4]); xn[5]=lrelu(a1.y*scP[5]+shP[5]);
    xn[6]=lrelu(a1.z*scP[6]+shP[6]); xn[7]=lrelu(a1.w*scP[7]+shP[7]);
    float s[16];
    #pragma unroll
    for(int o=0;o<16;o++) s[o]=0.f;
    #pragma unroll
    for(int c=0;c<16;c++){
      float xc = (c<8)? xn[c] : fx[c-8];
      #pragma unroll
      for(int o=0;o<16;o++) s[o] += Wa1[o*16+c]*xc;
    }
    #pragma unroll
    for(int c=0;c<8;c++){ xs[pg][c*17+l]=xn[c]; xs[pg][(8+c)*17+l]=fx[c]; }
    #pragma unroll
    for(int o=0;o<16;o++) ssc[pg][o*17+l]=s[o];
    __syncthreads();
    // lane l = row o now
    float sr[16];
    #pragma unroll
    for(int k=0;k<16;k++) sr[k]=ssc[pg][l*17+k];
    float mx=sr[0];
    #pragma unroll
    for(int k=1;k<16;k++) mx=fmaxf(mx,sr[k]);
    float sum=0.f;
    #pragma unroll
    for(int k=0;k<16;k++){ sr[k]=__expf(sr[k]-mx); sum+=sr[k]; }
    float rinv=1.0f/sum;
    float agg=0.f;
    #pragma unroll
    for(int k=0;k<16;k++) agg += sr[k]*rinv*xs[pg][l*17+k];
    aggv[pg][l]=agg;
    // lfa2 (register-only, own column fx)
    #pragma unroll
    for(int c=0;c<8;c++){
      float v = b2[c];
      #pragma unroll
      for(int j=0;j<8;j++) v += W2[c*8+j]*fx[j];
      l2s[c>>1]+=v; l2q[c>>1]+=v*v;
    }
    __syncthreads();
    if(l<8){
      float v = bm1[l];
      #pragma unroll
      for(int o=0;o<16;o++) v += Wm1[l*16+o]*aggv[pg][o];
      prem1[p*8+l] = v;
      m1s += v; m1q += v*v;
    }
    __syncthreads();
  }
  int lane = threadIdx.x & 63;
  #pragma unroll
  for(int g=0;g<4;g++){
    float a=wred(l2s[g]), qq=wred(l2q[g]);
    if(lane==0){ atomicAdd(&lst[g*2],a); atomicAdd(&lst[g*2+1],qq); }
  }
  if(l<8){
    int g = l>>1;
    atomicAdd(&lst[8+g*2],   m1s);
    atomicAdd(&lst[8+g*2+1], m1q);
  }
  __syncthreads();
  if(threadIdx.x<16){
    int half = threadIdx.x>>3;
    int g=(threadIdx.x>>1)&3, w=threadIdx.x&1;
    int stage = half? ST_M1 : ST_L2;
    atomicAdd(ws + ((stage*4+b)*4+g)*16 + w*8 + (blockIdx.x&7), lst[threadIdx.x]);
  }
}

// ---------------- K3: att-pool 2 (m2 pre+stats) ----------------
__global__ __launch_bounds__(256) void k3(
    const int* __restrict__ nidx,
    const float* __restrict__ WL1, const float* __restrict__ bl1,
    const float* __restrict__ gL1, const float* __restrict__ beL1,
    const float* __restrict__ W2,  const float* __restrict__ b2,
    const float* __restrict__ gL2, const float* __restrict__ beL2,
    const float* __restrict__ gm1, const float* __restrict__ bem1,
    const float* __restrict__ Wa2,
    const float* __restrict__ Wm2, const float* __restrict__ bm2,
    float* __restrict__ ws){
  int b = blockIdx.y;
  int l = threadIdx.x & 15;
  int pg = threadIdx.x >> 4;
  float scL[8], shL[8], scL2[8], shL2[8], scM[8], shM[8];
  #pragma unroll
  for(int g=0;g<4;g++){
    float m,inv;
    stat_fin(ws, ST_L1, b, g, 2.0f*NPTS*KNB, m, inv);
    #pragma unroll
    for(int u=0;u<2;u++){ int c=g*2+u; scL[c]=inv*gL1[c]; shL[c]=beL1[c]-m*inv*gL1[c]; }
    stat_fin(ws, ST_L2, b, g, 2.0f*NPTS*KNB, m, inv);
    #pragma unroll
    for(int u=0;u<2;u++){ int c=g*2+u; scL2[c]=inv*gL2[c]; shL2[c]=beL2[c]-m*inv*gL2[c]; }
    stat_fin(ws, ST_M1, b, g, 2.0f*NPTS, m, inv);
    #pragma unroll
    for(int u=0;u<2;u++){ int c=g*2+u; scM[c]=inv*gm1[c]; shM[c]=bem1[c]-m*inv*gm1[c]; }
  }
  const float4* xp = (const float4*)(ws + XYZP_OFF);
  const float* prem1 = ws + PREM1_OFF;
  float* prem2 = ws + PREM2_OFF;
  __shared__ float xs[16][272];
  __shared__ float ssc[16][272];
  __shared__ float aggv[16][16];
  __shared__ float lst[8];
  if(threadIdx.x<8) lst[threadIdx.x]=0.f;
  float m2s=0.f, m2q=0.f;

  for(int n0 = blockIdx.x*16 + pg; n0 < NPTS; n0 += gridDim.x*16){
    int p = (b<<LOGN) | n0;
    int idx = nidx[p*KNB + l];
    int pi = (b<<LOGN) | idx;
    float4 nb = xp[pi];
    float4 ct = xp[p];
    float rx=nb.x-ct.x, ry=nb.y-ct.y, rz=nb.z-ct.z;
    float dd = sqrtf(rx*rx+ry*ry+rz*rz);
    float fr[10] = {dd,rx,ry,rz,ct.x,ct.y,ct.z,nb.x,nb.y,nb.z};
    float fx[8];
    #pragma unroll
    for(int c=0;c<8;c++){
      float v = bl1[c];
      #pragma unroll
      for(int j=0;j<10;j++) v += WL1[c*10+j]*fr[j];
      fx[c] = lrelu(v*scL[c]+shL[c]);
    }
    float fx2[8];
    #pragma unroll
    for(int c=0;c<8;c++){
      float v = b2[c];
      #pragma unroll
      for(int j=0;j<8;j++) v += W2[c*8+j]*fx[j];
      fx2[c] = lrelu(v*scL2[c]+shL2[c]);
    }
    const float4* pr = (const float4*)(prem1 + pi*8);
    float4 a0=pr[0], a1=pr[1];
    float xn[8];
    xn[0]=lrelu(a0.x*scM[0]+shM[0]); xn[1]=lrelu(a0.y*scM[1]+shM[1]);
    xn[2]=lrelu(a0.z*scM[2]+shM[2]); xn[3]=lrelu(a0.w*scM[3]+shM[3]);
    xn[4]=lrelu(a1.x*scM[4]+shM[4]); xn[5]=lrelu(a1.y*scM[5]+shM[5]);
    xn[6]=lrelu(a1.z*scM[6]+shM[6]); xn[7]=lrelu(a1.w*scM[7]+shM[7]);
    float s[16];
    #pragma unroll
    for(int o=0;o<16;o++) s[o]=0.f;
    #pragma unroll
    for(int c=0;c<16;c++){
      float xc = (c<8)? xn[c] : fx2[c-8];
      #pragma unroll
      for(int o=0;o<16;o++) s[o] += Wa2[o*16+c]*xc;
    }
    #pragma unroll
    for(int c=0;c<8;c++){ xs[pg][c*17+l]=xn[c]; xs[pg][(8+c)*17+l]=fx2[c]; }
    #pragma unroll
    for(int o=0;o<16;o++) ssc[pg][o*17+l]=s[o];
    __syncthreads();
    float sr[16];
    #pragma unroll
    for(int k=0;k<16;k++) sr[k]=ssc[pg][l*17+k];
    float mx=sr[0];
    #pragma unroll
    for(int k=1;k<16;k++) mx=fmaxf(mx,sr[k]);
    float sum=0.f;
    #pragma unroll
    for(int k=0;k<16;k++){ sr[k]=__expf(sr[k]-mx); sum+=sr[k]; }
    float rinv=1.0f/sum;
    float agg=0.f;
    #pragma unroll
    for(int k=0;k<16;k++) agg += sr[k]*rinv*xs[pg][l*17+k];
    aggv[pg][l]=agg;
    __syncthreads();
    float v = bm2[l];
    #pragma unroll
    for(int o=0;o<16;o++) v += Wm2[l*16+o]*aggv[pg][o];
    prem2[p*16+l]=v;
    m2s+=v; m2q+=v*v;
    __syncthreads();
  }
  atomicAdd(&lst[(l>>2)*2],   m2s);
  atomicAdd(&lst[(l>>2)*2+1], m2q);
  __syncthreads();
  if(threadIdx.x<8){
    int g=(threadIdx.x>>1)&3, w=threadIdx.x&1;
    atomicAdd(ws + ((ST_M2*4+b)*4+g)*16 + w*8 + (blockIdx.x&7), lst[threadIdx.x]);
  }
}

// ---------------- K4: stats of mlp2 output ----------------
__global__ __launch_bounds__(256) void k4(
    const float* __restrict__ gm2, const float* __restrict__ bem2,
    const float* __restrict__ Wo,  const float* __restrict__ bo,
    float* __restrict__ ws){
  int b=blockIdx.y; int n=blockIdx.x*256+threadIdx.x; int p=(b<<LOGN)|n;
  float scM[16], shM[16];
  #pragma unroll
  for(int g=0;g<4;g++){
    float m,inv; stat_fin(ws, ST_M2, b, g, 4.0f*NPTS, m, inv);
    #pragma unroll
    for(int u=0;u<4;u++){ int c=g*4+u; scM[c]=inv*gm2[c]; shM[c]=bem2[c]-m*inv*gm2[c]; }
  }
  const float4* pm = (const float4*)(ws + PREM2_OFF) + p*4;
  float fa[16];
  #pragma unroll
  for(int i=0;i<4;i++){
    float4 v4 = pm[i];
    fa[i*4+0]=lrelu(v4.x*scM[i*4+0]+shM[i*4+0]);
    fa[i*4+1]=lrelu(v4.y*scM[i*4+1]+shM[i*4+1]);
    fa[i*4+2]=lrelu(v4.z*scM[i*4+2]+shM[i*4+2]);
    fa[i*4+3]=lrelu(v4.w*scM[i*4+3]+shM[i*4+3]);
  }
  float sos[4]={0,0,0,0}, soq[4]={0,0,0,0};
  #pragma unroll
  for(int o=0;o<32;o++){
    float v=bo[o];
    #pragma unroll
    for(int c=0;c<16;c++) v += Wo[o*16+c]*fa[c];
    sos[o>>3]+=v; soq[o>>3]+=v*v;
  }
  __shared__ float lst[8];
  if(threadIdx.x<8) lst[threadIdx.x]=0.f;
  __syncthreads();
  int lane = threadIdx.x & 63;
  #pragma unroll
  for(int g=0;g<4;g++){
    float a=wred(sos[g]), q=wred(soq[g]);
    if(lane==0){ atomicAdd(&lst[g*2],a); atomicAdd(&lst[g*2+1],q); }
  }
  __syncthreads();
  if(threadIdx.x<8){
    int g=(threadIdx.x>>1)&3, w=threadIdx.x&1;
    atomicAdd(ws + ((ST_OUT*4+b)*4+g)*16 + w*8 + (blockIdx.x&7), lst[threadIdx.x]);
  }
}

// ---------------- K5: final out = leaky(gn(mlp2) + gn(skip)) ----------------
__global__ __launch_bounds__(256) void k5(
    const float* __restrict__ feat,
    const float* __restrict__ gm2, const float* __restrict__ bem2,
    const float* __restrict__ Wo,  const float* __restrict__ bo,
    const float* __restrict__ go,  const float* __restrict__ beo,
    const float* __restrict__ Wsk, const float* __restrict__ bsk,
    const float* __restrict__ gsk, const float* __restrict__ besk,
    const float* __restrict__ ws, float* __restrict__ out){
  int b=blockIdx.y; int n=blockIdx.x*256+threadIdx.x; int p=(b<<LOGN)|n;
  float scM[16], shM[16];
  #pragma unroll
  for(int g=0;g<4;g++){
    float m,inv; stat_fin(ws, ST_M2, b, g, 4.0f*NPTS, m, inv);
    #pragma unroll
    for(int u=0;u<4;u++){ int c=g*4+u; scM[c]=inv*gm2[c]; shM[c]=bem2[c]-m*inv*gm2[c]; }
  }
  float mO[4], iO[4], mS[4], iS[4];
  #pragma unroll
  for(int g=0;g<4;g++){
    stat_fin(ws, ST_OUT,  b, g, 8.0f*NPTS, mO[g], iO[g]);
    stat_fin(ws, ST_SKIP, b, g, 8.0f*NPTS, mS[g], iS[g]);
  }
  const float4* pm = (const float4*)(ws + PREM2_OFF) + p*4;
  float fa[16];
  #pragma unroll
  for(int i=0;i<4;i++){
    float4 v4 = pm[i];
    fa[i*4+0]=lrelu(v4.x*scM[i*4+0]+shM[i*4+0]);
    fa[i*4+1]=lrelu(v4.y*scM[i*4+1]+shM[i*4+1]);
    fa[i*4+2]=lrelu(v4.z*scM[i*4+2]+shM[i*4+2]);
    fa[i*4+3]=lrelu(v4.w*scM[i*4+3]+shM[i*4+3]);
  }
  float f[8];
  #pragma unroll
  for(int c=0;c<8;c++) f[c]=feat[(b*8+c)*NPTS+n];
  #pragma unroll
  for(int o=0;o<32;o++){
    float to = bo[o];
    #pragma unroll
    for(int c=0;c<16;c++) to += Wo[o*16+c]*fa[c];
    float ts = bsk[o];
    #pragma unroll
    for(int j=0;j<8;j++) ts += Wsk[o*8+j]*f[j];
    int g=o>>3;
    float v = (to-mO[g])*iO[g]*go[o] + beo[o] + (ts-mS[g])*iS[g]*gsk[o] + besk[o];
    out[(b*32+o)*NPTS + n] = lrelu(v);
  }
}

extern "C" void kernel_launch(void* const* d_in, const int* in_sizes, int n_in,
                              void* d_out, int out_size, void* d_ws, size_t ws_size,
                              hipStream_t stream){
  (void)in_sizes; (void)n_in; (void)out_size; (void)ws_size;
  const float* feat=(const float*)d_in[0];
  const float* xyz =(const float*)d_in[1];
  const int*   nidx=(const int*)d_in[2];
  const float* W1  =(const float*)d_in[3];
  const float* b1  =(const float*)d_in[4];
  const float* g1  =(const float*)d_in[5];
  const float* be1 =(const float*)d_in[6];
  const float* WL1 =(const float*)d_in[7];
  const float* bl1 =(const float*)d_in[8];
  const float* gL1 =(const float*)d_in[9];
  const float* beL1=(const float*)d_in[10];
  const float* Wa1 =(const float*)d_in[11];
  const float* Wm1 =(const float*)d_in[12];
  const float* bm1 =(const float*)d_in[13];
  const float* gm1 =(const float*)d_in[14];
  const float* bem1=(const float*)d_in[15];
  const float* W2  =(const float*)d_in[16];
  const float* b2  =(const float*)d_in[17];
  const float* gL2 =(const float*)d_in[18];
  const float* beL2=(const float*)d_in[19];
  const float* Wa2 =(const float*)d_in[20];
  const float* Wm2 =(const float*)d_in[21];
  const float* bm2 =(const float*)d_in[22];
  const float* gm2 =(const float*)d_in[23];
  const float* bem2=(const float*)d_in[24];
  const float* Wo  =(const float*)d_in[25];
  const float* bo  =(const float*)d_in[26];
  const float* go  =(const float*)d_in[27];
  const float* beo =(const float*)d_in[28];
  const float* Wsk =(const float*)d_in[29];
  const float* bsk =(const float*)d_in[30];
  const float* gsk =(const float*)d_in[31];
  const float* besk=(const float*)d_in[32];
  float* ws=(float*)d_ws;
  float* out=(float*)d_out;

  hipMemsetAsync(d_ws, 0, STAT_F*sizeof(float), stream);
  k_pack<<<dim3(1024),dim3(256),0,stream>>>(xyz, ws);
  k1<<<dim3(256,4),dim3(256),0,stream>>>(feat, nidx, W1,b1, Wsk,bsk, WL1,bl1, ws);
  k2<<<dim3(512,4),dim3(256),0,stream>>>(nidx, WL1,bl1,gL1,beL1, g1,be1, Wa1, Wm1,bm1, W2,b2, ws);
  k3<<<dim3(512,4),dim3(256),0,stream>>>(nidx, WL1,bl1,gL1,beL1, W2,b2,gL2,beL2, gm1,bem1, Wa2, Wm2,bm2, ws);
  k4<<<dim3(256,4),dim3(256),0,stream>>>(gm2,bem2, Wo,bo, ws);
  k5<<<dim3(256,4),dim3(256),0,stream>>>(feat, gm2,bem2, Wo,bo, go,beo, Wsk,bsk, gsk,besk, ws, out);
}

// Round 2
// 335.908 us; speedup vs baseline: 3.0110x; 3.0110x over previous
//
#include <hip/hip_runtime.h>

#define NPTS 65536
#define LOGN 16
#define KNB 16
#define NEGS 0.2f
#define EPSV 1e-5f

// GN stages
#define ST_MLP1 0
#define ST_SKIP 1
#define ST_L1   2
#define ST_M1   3
#define ST_L2   4
#define ST_M2   5
#define ST_OUT  6

// ws layout (floats): raw stats | finalized (scale,shift) | xyz packed | pre1 | prem1 | prem2
// raw stats: per (stage,b,g): 128 floats = [64 sum slots][64 sumsq slots]
#define STAT_F   14336                       // 7*4*4*128
#define FIN_OFF  14336                       // 7*4*32*2 = 1792
#define XYZP_OFF 16384
#define PRE1_OFF  (XYZP_OFF + 4*NPTS*4)      // 1,064,960
#define PREM1_OFF (PRE1_OFF + 4*NPTS*8)      // 3,162,112
#define PREM2_OFF (PREM1_OFF + 4*NPTS*8)     // 5,259,264
// total = PREM2_OFF + 4*NPTS*16 = 9,453,568 floats (~37.8 MB)

__device__ __forceinline__ float lrelu(float v){ return v >= 0.f ? v : v*NEGS; }

__device__ __forceinline__ float wred(float v){
  #pragma unroll
  for(int off=32; off>0; off>>=1) v += __shfl_xor(v, off, 64);
  return v;
}

__device__ __forceinline__ void wave_fence(){
  __builtin_amdgcn_sched_barrier(0);
  asm volatile("s_waitcnt lgkmcnt(0)" ::: "memory");
  __builtin_amdgcn_sched_barrier(0);
}

__device__ __forceinline__ void load_fin(const float* fin, int stage, int b, int c,
                                         float& sc, float& sh){
  const float* fp = fin + ((stage*4+b)*32 + c)*2;
  sc = fp[0]; sh = fp[1];
}

// ---------------- K0: pack xyz -> float4 [b][n] ----------------
__global__ __launch_bounds__(256) void k_pack(const float* __restrict__ xyz,
                                              float* __restrict__ ws){
  int p = blockIdx.x*256 + threadIdx.x;
  int b = p >> LOGN, n = p & (NPTS-1);
  const float* xb = xyz + b*3*NPTS + n;
  float4 v = make_float4(xb[0], xb[NPTS], xb[2*NPTS], 0.f);
  ((float4*)(ws + XYZP_OFF))[p] = v;
}

// ---------------- fin: raw slots -> (scale,shift) per channel ----------------
__device__ void fin_stage(const float* __restrict__ ws, float* __restrict__ fin,
                          int stage, int nch, float cnt,
                          const float* __restrict__ gamma, const float* __restrict__ beta){
  int t = threadIdx.x;
  if(t >= 4*nch) return;
  int b = t / nch, c = t - b*nch;
  int g = c / (nch/4);
  const float* sl = ws + ((stage*4+b)*4+g)*128;
  float s=0.f, q=0.f;
  #pragma unroll 8
  for(int i=0;i<64;i++){ s += sl[i]; q += sl[64+i]; }
  float mean = s/cnt;
  float var  = q/cnt - mean*mean;
  float inv  = rsqrtf(var + EPSV);
  float sc = inv*gamma[c];
  float sh = beta[c] - mean*sc;
  float* fp = fin + ((stage*4+b)*32 + c)*2;
  fp[0]=sc; fp[1]=sh;
}

__global__ __launch_bounds__(128) void kfA(float* __restrict__ ws,
    const float* g1, const float* be1, const float* gL1, const float* beL1,
    const float* gsk, const float* besk){
  if(blockIdx.x==0)      fin_stage(ws, ws+FIN_OFF, ST_MLP1, 8,  2.0f*NPTS,      g1, be1);
  else if(blockIdx.x==1) fin_stage(ws, ws+FIN_OFF, ST_L1,   8,  2.0f*NPTS*KNB,  gL1, beL1);
  else                   fin_stage(ws, ws+FIN_OFF, ST_SKIP, 32, 8.0f*NPTS,      gsk, besk);
}
__global__ __launch_bounds__(128) void kfB(float* __restrict__ ws,
    const float* gm1, const float* bem1, const float* gL2, const float* beL2){
  if(blockIdx.x==0) fin_stage(ws, ws+FIN_OFF, ST_M1, 8, 2.0f*NPTS,     gm1, bem1);
  else              fin_stage(ws, ws+FIN_OFF, ST_L2, 8, 2.0f*NPTS*KNB, gL2, beL2);
}
__global__ __launch_bounds__(128) void kfC(float* __restrict__ ws,
    const float* gm2, const float* bem2){
  fin_stage(ws, ws+FIN_OFF, ST_M2, 16, 4.0f*NPTS, gm2, bem2);
}
__global__ __launch_bounds__(128) void kfD(float* __restrict__ ws,
    const float* go, const float* beo){
  fin_stage(ws, ws+FIN_OFF, ST_OUT, 32, 8.0f*NPTS, go, beo);
}

// ---------------- K1: mlp1 pre + stats; skip stats; lfa1 stats ----------------
__global__ __launch_bounds__(256) void k1(
    const float* __restrict__ feat, const int* __restrict__ nidx,
    const float* __restrict__ W1,  const float* __restrict__ b1,
    const float* __restrict__ Ws,  const float* __restrict__ bs,
    const float* __restrict__ WL1, const float* __restrict__ bl1,
    float* __restrict__ ws){
  int b = blockIdx.y;
  int n = blockIdx.x*256 + threadIdx.x;
  int p = (b<<LOGN) | n;
  float f[8];
  #pragma unroll
  for(int c=0;c<8;c++) f[c] = feat[(b*8+c)*NPTS + n];
  float* pre1 = ws + PRE1_OFF;

  float s1s[4]={0,0,0,0}, s1q[4]={0,0,0,0};
  float pv[8];
  #pragma unroll
  for(int c=0;c<8;c++){
    float v = b1[c];
    #pragma unroll
    for(int j=0;j<8;j++) v += W1[c*8+j]*f[j];
    pv[c]=v;
    s1s[c>>1]+=v; s1q[c>>1]+=v*v;
  }
  float4* pr = (float4*)(pre1 + p*8);
  pr[0] = make_float4(pv[0],pv[1],pv[2],pv[3]);
  pr[1] = make_float4(pv[4],pv[5],pv[6],pv[7]);

  float sss[4]={0,0,0,0}, ssq[4]={0,0,0,0};
  #pragma unroll
  for(int o=0;o<32;o++){
    float v = bs[o];
    #pragma unroll
    for(int j=0;j<8;j++) v += Ws[o*8+j]*f[j];
    sss[o>>3]+=v; ssq[o>>3]+=v*v;
  }
  const float4* xp = (const float4*)(ws + XYZP_OFF);
  float4 ct = xp[p];
  float l1s[4]={0,0,0,0}, l1q[4]={0,0,0,0};
  const int* nr = nidx + p*KNB;
  #pragma unroll
  for(int k=0;k<KNB;k++){
    int idx = nr[k];
    float4 nb = xp[(b<<LOGN)|idx];
    float rx=nb.x-ct.x, ry=nb.y-ct.y, rz=nb.z-ct.z;
    float dd = sqrtf(rx*rx+ry*ry+rz*rz);
    float fr[10] = {dd,rx,ry,rz,ct.x,ct.y,ct.z,nb.x,nb.y,nb.z};
    #pragma unroll
    for(int c=0;c<8;c++){
      float v = bl1[c];
      #pragma unroll
      for(int j=0;j<10;j++) v += WL1[c*10+j]*fr[j];
      l1s[c>>1]+=v; l1q[c>>1]+=v*v;
    }
  }
  __shared__ float lst[24];
  if(threadIdx.x < 24) lst[threadIdx.x] = 0.f;
  __syncthreads();
  int lane = threadIdx.x & 63;
  #pragma unroll
  for(int g=0; g<4; g++){
    float a1v = wred(s1s[g]), a2v = wred(s1q[g]);
    float d1v = wred(sss[g]), d2v = wred(ssq[g]);
    float e1v = wred(l1s[g]), e2v = wred(l1q[g]);
    if(lane==0){
      atomicAdd(&lst[ 0+g*2], a1v); atomicAdd(&lst[ 1+g*2], a2v);
      atomicAdd(&lst[ 8+g*2], d1v); atomicAdd(&lst[ 9+g*2], d2v);
      atomicAdd(&lst[16+g*2], e1v); atomicAdd(&lst[17+g*2], e2v);
    }
  }
  __syncthreads();
  if(threadIdx.x < 24){
    int stage = threadIdx.x >> 3;          // 0=MLP1,1=SKIP,2=L1
    int g = (threadIdx.x >> 1) & 3;
    int w = threadIdx.x & 1;
    atomicAdd(ws + ((stage*4+b)*4+g)*128 + w*64 + (blockIdx.x&63), lst[threadIdx.x]);
  }
}

// ---------------- K2: att-pool 1 (wave-local, barrier-free) ----------------
__global__ __launch_bounds__(256,4) void k2(
    const int* __restrict__ nidx,
    const float* __restrict__ WL1, const float* __restrict__ bl1,
    const float* __restrict__ Wa1,
    const float* __restrict__ Wm1, const float* __restrict__ bm1,
    const float* __restrict__ W2,  const float* __restrict__ b2,
    float* __restrict__ ws){
  const float* fin = ws + FIN_OFF;
  int b = blockIdx.y;
  int tid = threadIdx.x;
  int w = tid>>6, lane = tid&63, pg = lane>>4, l = lane&15;
  int n0 = blockIdx.x*16 + w*4 + pg;
  int p = (b<<LOGN) | n0;

  float scP[8], shP[8], scL[8], shL[8];
  #pragma unroll
  for(int c=0;c<8;c++){
    load_fin(fin, ST_MLP1,b,c, scP[c],shP[c]);
    load_fin(fin, ST_L1,  b,c, scL[c],shL[c]);
  }
  float wm[16];
  #pragma unroll
  for(int o=0;o<16;o++) wm[o] = Wm1[(l&7)*16+o];

  __shared__ float SB[4][2244];
  __shared__ float lst[16];
  if(tid<16) lst[tid]=0.f;
  float* xs  = &SB[w][pg*272];          // [c*17 + col]
  float* ssp = &SB[w][1088 + pg*272];
  float* agv = &SB[w][2176 + pg*17];

  const float4* xp = (const float4*)(ws + XYZP_OFF);
  const float* pre1 = ws + PRE1_OFF;
  float* prem1 = ws + PREM1_OFF;

  int idx = nidx[p*KNB + l];
  int pi = (b<<LOGN) | idx;
  float4 nb = xp[pi], ct = xp[p];
  float rx=nb.x-ct.x, ry=nb.y-ct.y, rz=nb.z-ct.z;
  float dd = sqrtf(rx*rx+ry*ry+rz*rz);
  float fr[10] = {dd,rx,ry,rz,ct.x,ct.y,ct.z,nb.x,nb.y,nb.z};
  float fx[8];
  #pragma unroll
  for(int c=0;c<8;c++){
    float v = bl1[c];
    #pragma unroll
    for(int j=0;j<10;j++) v += WL1[c*10+j]*fr[j];
    fx[c] = lrelu(v*scL[c]+shL[c]);
  }
  float xn[8];
  const float4* pr = (const float4*)(pre1 + pi*8);
  float4 a0=pr[0], a1=pr[1];
  xn[0]=lrelu(a0.x*scP[0]+shP[0]); xn[1]=lrelu(a0.y*scP[1]+shP[1]);
  xn[2]=lrelu(a0.z*scP[2]+shP[2]); xn[3]=lrelu(a0.w*scP[3]+shP[3]);
  xn[4]=lrelu(a1.x*scP[4]+shP[4]); xn[5]=lrelu(a1.y*scP[5]+shP[5]);
  xn[6]=lrelu(a1.z*scP[6]+shP[6]); xn[7]=lrelu(a1.w*scP[7]+shP[7]);

  #pragma unroll
  for(int c=0;c<8;c++){ xs[c*17+l]=xn[c]; xs[(8+c)*17+l]=fx[c]; }

  float s[16];
  #pragma unroll
  for(int o=0;o<16;o++) s[o]=0.f;
  #pragma unroll
  for(int c=0;c<16;c++){
    float xc = (c<8)? xn[c] : fx[c-8];
    #pragma unroll
    for(int o=0;o<16;o++) s[o] += Wa1[o*16+c]*xc;
  }
  #pragma unroll
  for(int o=0;o<16;o++) ssp[o*17+l]=s[o];

  wave_fence();

  float sr[16];
  #pragma unroll
  for(int k=0;k<16;k++) sr[k]=ssp[l*17+k];
  float mx=sr[0];
  #pragma unroll
  for(int k=1;k<16;k++) mx=fmaxf(mx,sr[k]);
  float sum=0.f;
  #pragma unroll
  for(int k=0;k<16;k++){ sr[k]=__expf(sr[k]-mx); sum+=sr[k]; }
  float acc=0.f;
  #pragma unroll
  for(int k=0;k<16;k++) acc += sr[k]*xs[l*17+k];
  float agg = acc/sum;
  agv[l]=agg;

  // lfa2 pre-GN stats from own column fx
  float l2s[4]={0,0,0,0}, l2q[4]={0,0,0,0};
  #pragma unroll
  for(int c=0;c<8;c++){
    float v = b2[c];
    #pragma unroll
    for(int j=0;j<8;j++) v += W2[c*8+j]*fx[j];
    l2s[c>>1]+=v; l2q[c>>1]+=v*v;
  }

  wave_fence();

  float am[16];
  #pragma unroll
  for(int o=0;o<16;o++) am[o]=agv[o];
  float m1v=0.f;
  bool doM1 = (l<8);
  if(doM1){
    float v = bm1[l];
    #pragma unroll
    for(int o=0;o<16;o++) v += wm[o]*am[o];
    prem1[p*8+l]=v;
    m1v=v;
  }

  __syncthreads();   // lst zero-init visible before atomics
  #pragma unroll
  for(int g=0;g<4;g++){
    float a=wred(l2s[g]), q=wred(l2q[g]);
    if(lane==0){ atomicAdd(&lst[g*2],a); atomicAdd(&lst[g*2+1],q); }
  }
  if(doM1){
    atomicAdd(&lst[8+(l>>1)*2],   m1v);
    atomicAdd(&lst[8+(l>>1)*2+1], m1v*m1v);
  }
  __syncthreads();
  if(tid<16){
    int half=tid>>3, g=(tid>>1)&3, wsel=tid&1;
    int stage = half? ST_M1 : ST_L2;
    atomicAdd(ws + ((stage*4+b)*4+g)*128 + wsel*64 + (blockIdx.x&63), lst[tid]);
  }
}

// ---------------- K3: att-pool 2 (wave-local, barrier-free) ----------------
__global__ __launch_bounds__(256,4) void k3(
    const int* __restrict__ nidx,
    const float* __restrict__ WL1, const float* __restrict__ bl1,
    const float* __restrict__ W2,  const float* __restrict__ b2,
    const float* __restrict__ Wa2,
    const float* __restrict__ Wm2, const float* __restrict__ bm2,
    float* __restrict__ ws){
  const float* fin = ws + FIN_OFF;
  int b = blockIdx.y;
  int tid = threadIdx.x;
  int w = tid>>6, lane = tid&63, pg = lane>>4, l = lane&15;
  int n0 = blockIdx.x*16 + w*4 + pg;
  int p = (b<<LOGN) | n0;

  float scL[8], shL[8], scL2[8], shL2[8], scM[8], shM[8];
  #pragma unroll
  for(int c=0;c<8;c++){
    load_fin(fin, ST_L1, b,c, scL[c], shL[c]);
    load_fin(fin, ST_L2, b,c, scL2[c],shL2[c]);
    load_fin(fin, ST_M1, b,c, scM[c], shM[c]);
  }
  float wm[16];
  #pragma unroll
  for(int o=0;o<16;o++) wm[o] = Wm2[l*16+o];

  __shared__ float SB[4][2244];
  __shared__ float lst[8];
  if(tid<8) lst[tid]=0.f;
  float* xs  = &SB[w][pg*272];
  float* ssp = &SB[w][1088 + pg*272];
  float* agv = &SB[w][2176 + pg*17];

  const float4* xp = (const float4*)(ws + XYZP_OFF);
  const float* prem1 = ws + PREM1_OFF;
  float* prem2 = ws + PREM2_OFF;

  int idx = nidx[p*KNB + l];
  int pi = (b<<LOGN) | idx;
  float4 nb = xp[pi], ct = xp[p];
  float rx=nb.x-ct.x, ry=nb.y-ct.y, rz=nb.z-ct.z;
  float dd = sqrtf(rx*rx+ry*ry+rz*rz);
  float fr[10] = {dd,rx,ry,rz,ct.x,ct.y,ct.z,nb.x,nb.y,nb.z};
  float fx[8];
  #pragma unroll
  for(int c=0;c<8;c++){
    float v = bl1[c];
    #pragma unroll
    for(int j=0;j<10;j++) v += WL1[c*10+j]*fr[j];
    fx[c] = lrelu(v*scL[c]+shL[c]);
  }
  float fx2[8];
  #pragma unroll
  for(int c=0;c<8;c++){
    float v = b2[c];
    #pragma unroll
    for(int j=0;j<8;j++) v += W2[c*8+j]*fx[j];
    fx2[c] = lrelu(v*scL2[c]+shL2[c]);
  }
  float xn[8];
  const float4* prr = (const float4*)(prem1 + pi*8);
  float4 a0=prr[0], a1=prr[1];
  xn[0]=lrelu(a0.x*scM[0]+shM[0]); xn[1]=lrelu(a0.y*scM[1]+shM[1]);
  xn[2]=lrelu(a0.z*scM[2]+shM[2]); xn[3]=lrelu(a0.w*scM[3]+shM[3]);
  xn[4]=lrelu(a1.x*scM[4]+shM[4]); xn[5]=lrelu(a1.y*scM[5]+shM[5]);
  xn[6]=lrelu(a1.z*scM[6]+shM[6]); xn[7]=lrelu(a1.w*scM[7]+shM[7]);

  #pragma unroll
  for(int c=0;c<8;c++){ xs[c*17+l]=xn[c]; xs[(8+c)*17+l]=fx2[c]; }

  float s[16];
  #pragma unroll
  for(int o=0;o<16;o++) s[o]=0.f;
  #pragma unroll
  for(int c=0;c<16;c++){
    float xc = (c<8)? xn[c] : fx2[c-8];
    #pragma unroll
    for(int o=0;o<16;o++) s[o] += Wa2[o*16+c]*xc;
  }
  #pragma unroll
  for(int o=0;o<16;o++) ssp[o*17+l]=s[o];

  wave_fence();

  float sr[16];
  #pragma unroll
  for(int k=0;k<16;k++) sr[k]=ssp[l*17+k];
  float mx=sr[0];
  #pragma unroll
  for(int k=1;k<16;k++) mx=fmaxf(mx,sr[k]);
  float sum=0.f;
  #pragma unroll
  for(int k=0;k<16;k++){ sr[k]=__expf(sr[k]-mx); sum+=sr[k]; }
  float acc=0.f;
  #pragma unroll
  for(int k=0;k<16;k++) acc += sr[k]*xs[l*17+k];
  float agg = acc/sum;
  agv[l]=agg;

  wave_fence();

  float am[16];
  #pragma unroll
  for(int o=0;o<16;o++) am[o]=agv[o];
  float v = bm2[l];
  #pragma unroll
  for(int o=0;o<16;o++) v += wm[o]*am[o];
  prem2[p*16+l]=v;

  __syncthreads();
  atomicAdd(&lst[(l>>2)*2],   v);
  atomicAdd(&lst[(l>>2)*2+1], v*v);
  __syncthreads();
  if(tid<8){
    int g=(tid>>1)&3, wsel=tid&1;
    atomicAdd(ws + ((ST_M2*4+b)*4+g)*128 + wsel*64 + (blockIdx.x&63), lst[tid]);
  }
}

// ---------------- K4: stats of mlp2 output ----------------
__global__ __launch_bounds__(256) void k4(
    const float* __restrict__ Wo,  const float* __restrict__ bo,
    float* __restrict__ ws){
  const float* fin = ws + FIN_OFF;
  int b=blockIdx.y; int n=blockIdx.x*256+threadIdx.x; int p=(b<<LOGN)|n;
  float scM[16], shM[16];
  #pragma unroll
  for(int c=0;c<16;c++) load_fin(fin, ST_M2, b, c, scM[c], shM[c]);
  const float4* pm = (const float4*)(ws + PREM2_OFF) + p*4;
  float fa[16];
  #pragma unroll
  for(int i=0;i<4;i++){
    float4 v4 = pm[i];
    fa[i*4+0]=lrelu(v4.x*scM[i*4+0]+shM[i*4+0]);
    fa[i*4+1]=lrelu(v4.y*scM[i*4+1]+shM[i*4+1]);
    fa[i*4+2]=lrelu(v4.z*scM[i*4+2]+shM[i*4+2]);
    fa[i*4+3]=lrelu(v4.w*scM[i*4+3]+shM[i*4+3]);
  }
  float sos[4]={0,0,0,0}, soq[4]={0,0,0,0};
  #pragma unroll
  for(int o=0;o<32;o++){
    float v=bo[o];
    #pragma unroll
    for(int c=0;c<16;c++) v += Wo[o*16+c]*fa[c];
    sos[o>>3]+=v; soq[o>>3]+=v*v;
  }
  __shared__ float lst[8];
  if(threadIdx.x<8) lst[threadIdx.x]=0.f;
  __syncthreads();
  int lane = threadIdx.x & 63;
  #pragma unroll
  for(int g=0;g<4;g++){
    float a=wred(sos[g]), q=wred(soq[g]);
    if(lane==0){ atomicAdd(&lst[g*2],a); atomicAdd(&lst[g*2+1],q); }
  }
  __syncthreads();
  if(threadIdx.x<8){
    int g=(threadIdx.x>>1)&3, w=threadIdx.x&1;
    atomicAdd(ws + ((ST_OUT*4+b)*4+g)*128 + w*64 + (blockIdx.x&63), lst[threadIdx.x]);
  }
}

// ---------------- K5: final out = leaky(gn(mlp2) + gn(skip)) ----------------
__global__ __launch_bounds__(256) void k5(
    const float* __restrict__ feat,
    const float* __restrict__ Wo,  const float* __restrict__ bo,
    const float* __restrict__ Wsk, const float* __restrict__ bsk,
    const float* __restrict__ ws, float* __restrict__ out){
  const float* fin = ws + FIN_OFF;
  int b=blockIdx.y; int n=blockIdx.x*256+threadIdx.x; int p=(b<<LOGN)|n;
  float scM[16], shM[16];
  #pragma unroll
  for(int c=0;c<16;c++) load_fin(fin, ST_M2, b, c, scM[c], shM[c]);
  const float4* pm = (const float4*)(ws + PREM2_OFF) + p*4;
  float fa[16];
  #pragma unroll
  for(int i=0;i<4;i++){
    float4 v4 = pm[i];
    fa[i*4+0]=lrelu(v4.x*scM[i*4+0]+shM[i*4+0]);
    fa[i*4+1]=lrelu(v4.y*scM[i*4+1]+shM[i*4+1]);
    fa[i*4+2]=lrelu(v4.z*scM[i*4+2]+shM[i*4+2]);
    fa[i*4+3]=lrelu(v4.w*scM[i*4+3]+shM[i*4+3]);
  }
  float f[8];
  #pragma unroll
  for(int c=0;c<8;c++) f[c]=feat[(b*8+c)*NPTS+n];
  #pragma unroll
  for(int o=0;o<32;o++){
    float to = bo[o];
    #pragma unroll
    for(int c=0;c<16;c++) to += Wo[o*16+c]*fa[c];
    float ts = bsk[o];
    #pragma unroll
    for(int j=0;j<8;j++) ts += Wsk[o*8+j]*f[j];
    float scO, shO, scS, shS;
    load_fin(fin, ST_OUT,  b, o, scO, shO);
    load_fin(fin, ST_SKIP, b, o, scS, shS);
    float v = to*scO+shO + ts*scS+shS;
    out[(b*32+o)*NPTS + n] = lrelu(v);
  }
}

extern "C" void kernel_launch(void* const* d_in, const int* in_sizes, int n_in,
                              void* d_out, int out_size, void* d_ws, size_t ws_size,
                              hipStream_t stream){
  (void)in_sizes; (void)n_in; (void)out_size; (void)ws_size;
  const float* feat=(const float*)d_in[0];
  const float* xyz =(const float*)d_in[1];
  const int*   nidx=(const int*)d_in[2];
  const float* W1  =(const float*)d_in[3];
  const float* b1  =(const float*)d_in[4];
  const float* g1  =(const float*)d_in[5];
  const float* be1 =(const float*)d_in[6];
  const float* WL1 =(const float*)d_in[7];
  const float* bl1 =(const float*)d_in[8];
  const float* gL1 =(const float*)d_in[9];
  const float* beL1=(const float*)d_in[10];
  const float* Wa1 =(const float*)d_in[11];
  const float* Wm1 =(const float*)d_in[12];
  const float* bm1 =(const float*)d_in[13];
  const float* gm1 =(const float*)d_in[14];
  const float* bem1=(const float*)d_in[15];
  const float* W2  =(const float*)d_in[16];
  const float* b2  =(const float*)d_in[17];
  const float* gL2 =(const float*)d_in[18];
  const float* beL2=(const float*)d_in[19];
  const float* Wa2 =(const float*)d_in[20];
  const float* Wm2 =(const float*)d_in[21];
  const float* bm2 =(const float*)d_in[22];
  const float* gm2 =(const float*)d_in[23];
  const float* bem2=(const float*)d_in[24];
  const float* Wo  =(const float*)d_in[25];
  const float* bo  =(const float*)d_in[26];
  const float* go  =(const float*)d_in[27];
  const float* beo =(const float*)d_in[28];
  const float* Wsk =(const float*)d_in[29];
  const float* bsk =(const float*)d_in[30];
  const float* gsk =(const float*)d_in[31];
  const float* besk=(const float*)d_in[32];
  float* ws=(float*)d_ws;
  float* out=(float*)d_out;

  hipMemsetAsync(d_ws, 0, STAT_F*sizeof(float), stream);
  k_pack<<<dim3(1024),dim3(256),0,stream>>>(xyz, ws);
  k1<<<dim3(256,4),dim3(256),0,stream>>>(feat, nidx, W1,b1, Wsk,bsk, WL1,bl1, ws);
  kfA<<<dim3(3),dim3(128),0,stream>>>(ws, g1,be1, gL1,beL1, gsk,besk);
  k2<<<dim3(4096,4),dim3(256),0,stream>>>(nidx, WL1,bl1, Wa1, Wm1,bm1, W2,b2, ws);
  kfB<<<dim3(2),dim3(128),0,stream>>>(ws, gm1,bem1, gL2,beL2);
  k3<<<dim3(4096,4),dim3(256),0,stream>>>(nidx, WL1,bl1, W2,b2, Wa2, Wm2,bm2, ws);
  kfC<<<dim3(1),dim3(128),0,stream>>>(ws, gm2,bem2);
  k4<<<dim3(256,4),dim3(256),0,stream>>>(Wo,bo, ws);
  kfD<<<dim3(1),dim3(128),0,stream>>>(ws, go,beo);
  k5<<<dim3(256,4),dim3(256),0,stream>>>(feat, Wo,bo, Wsk,bsk, ws, out);
}

// Round 3
// 318.879 us; speedup vs baseline: 3.1718x; 1.0534x over previous
//
#include <hip/hip_runtime.h>
#include <hip/hip_bf16.h>

#define NPTS 65536
#define LOGN 16
#define KNB 16
#define NEGS 0.2f
#define EPSV 1e-5f

// GN stages
#define ST_MLP1 0
#define ST_SKIP 1
#define ST_L1   2
#define ST_M1   3
#define ST_L2   4
#define ST_M2   5
#define ST_OUT  6

// ws layout (floats): raw stats | finalized (scale,shift) | xyz packed | pre1 | prem1 | prem2
#define STAT_F   14336                       // 7*4*4*128
#define FIN_OFF  14336                       // 7*4*32*2 = 1792
#define XYZP_OFF 16384
#define PRE1_OFF  (XYZP_OFF + 4*NPTS*4)
#define PREM1_OFF (PRE1_OFF + 4*NPTS*8)
#define PREM2_OFF (PREM1_OFF + 4*NPTS*8)

typedef __attribute__((ext_vector_type(8))) short short8;
typedef __attribute__((ext_vector_type(4))) float f32x4;

union U16 { uint4 u; short8 s; };

__device__ __forceinline__ float lrelu(float v){ return fmaxf(v, v*NEGS); }

__device__ __forceinline__ float wred(float v){
  #pragma unroll
  for(int off=32; off>0; off>>=1) v += __shfl_xor(v, off, 64);
  return v;
}

__device__ __forceinline__ void wave_fence(){
  __builtin_amdgcn_sched_barrier(0);
  asm volatile("s_waitcnt lgkmcnt(0)" ::: "memory");
  __builtin_amdgcn_sched_barrier(0);
}

__device__ __forceinline__ void load_fin(const float* fin, int stage, int b, int c,
                                         float& sc, float& sh){
  const float* fp = fin + ((stage*4+b)*32 + c)*2;
  sc = fp[0]; sh = fp[1];
}

__device__ __forceinline__ unsigned pkbf(float a, float b){
  __hip_bfloat162 h = __float22bfloat162_rn(make_float2(a,b));
  union{ __hip_bfloat162 h2; unsigned u; } cv; cv.h2 = h; return cv.u;
}
__device__ __forceinline__ float blo(unsigned d){ return __builtin_bit_cast(float, d<<16); }
__device__ __forceinline__ float bhi(unsigned d){ return __builtin_bit_cast(float, d & 0xffff0000u); }

// per-wave LDS byte offsets (within 6432-byte wave region)
#define XB_OFF 0        // bf16 B-frag planes: 2 x 1024B, addr = h*1024 + (pg*16+k)*16
#define XR_OFF 2048     // bf16 x rows: [pg][o][k]: pg*512 + o*32 + k*2
#define SS_OFF 4096     // bf16 score rows: [pg][o][k]: pg*512 + o*32 + k*2
#define AG_OFF 6144     // f32 agg: [pg][17]: pg*68 + o*4
#define WV_BYTES 6432

// ---------------- K0: pack xyz -> float4 [b][n] ----------------
__global__ __launch_bounds__(256) void k_pack(const float* __restrict__ xyz,
                                              float* __restrict__ ws){
  int p = blockIdx.x*256 + threadIdx.x;
  int b = p >> LOGN, n = p & (NPTS-1);
  const float* xb = xyz + b*3*NPTS + n;
  float4 v = make_float4(xb[0], xb[NPTS], xb[2*NPTS], 0.f);
  ((float4*)(ws + XYZP_OFF))[p] = v;
}

// ---------------- fin: raw slots -> (scale,shift) per channel ----------------
__device__ void fin_stage(const float* __restrict__ ws, float* __restrict__ fin,
                          int stage, int nch, float cnt,
                          const float* __restrict__ gamma, const float* __restrict__ beta){
  int t = threadIdx.x;
  if(t >= 4*nch) return;
  int b = t / nch, c = t - b*nch;
  int g = c / (nch/4);
  const float* sl = ws + ((stage*4+b)*4+g)*128;
  float s=0.f, q=0.f;
  #pragma unroll 8
  for(int i=0;i<64;i++){ s += sl[i]; q += sl[64+i]; }
  float mean = s/cnt;
  float var  = q/cnt - mean*mean;
  float inv  = rsqrtf(var + EPSV);
  float sc = inv*gamma[c];
  float sh = beta[c] - mean*sc;
  float* fp = fin + ((stage*4+b)*32 + c)*2;
  fp[0]=sc; fp[1]=sh;
}

__global__ __launch_bounds__(128) void kfA(float* __restrict__ ws,
    const float* g1, const float* be1, const float* gL1, const float* beL1,
    const float* gsk, const float* besk){
  if(blockIdx.x==0)      fin_stage(ws, ws+FIN_OFF, ST_MLP1, 8,  2.0f*NPTS,      g1, be1);
  else if(blockIdx.x==1) fin_stage(ws, ws+FIN_OFF, ST_L1,   8,  2.0f*NPTS*KNB,  gL1, beL1);
  else                   fin_stage(ws, ws+FIN_OFF, ST_SKIP, 32, 8.0f*NPTS,      gsk, besk);
}
__global__ __launch_bounds__(128) void kfB(float* __restrict__ ws,
    const float* gm1, const float* bem1, const float* gL2, const float* beL2){
  if(blockIdx.x==0) fin_stage(ws, ws+FIN_OFF, ST_M1, 8, 2.0f*NPTS,     gm1, bem1);
  else              fin_stage(ws, ws+FIN_OFF, ST_L2, 8, 2.0f*NPTS*KNB, gL2, beL2);
}
__global__ __launch_bounds__(128) void kfC(float* __restrict__ ws,
    const float* gm2, const float* bem2){
  fin_stage(ws, ws+FIN_OFF, ST_M2, 16, 4.0f*NPTS, gm2, bem2);
}
__global__ __launch_bounds__(128) void kfD(float* __restrict__ ws,
    const float* go, const float* beo){
  fin_stage(ws, ws+FIN_OFF, ST_OUT, 32, 8.0f*NPTS, go, beo);
}

// ---------------- K1: mlp1 pre + stats; skip stats; lfa1 stats ----------------
__global__ __launch_bounds__(256) void k1(
    const float* __restrict__ feat, const int* __restrict__ nidx,
    const float* __restrict__ W1,  const float* __restrict__ b1,
    const float* __restrict__ Ws,  const float* __restrict__ bs,
    const float* __restrict__ WL1, const float* __restrict__ bl1,
    float* __restrict__ ws){
  int b = blockIdx.y;
  int n = blockIdx.x*256 + threadIdx.x;
  int p = (b<<LOGN) | n;
  float f[8];
  #pragma unroll
  for(int c=0;c<8;c++) f[c] = feat[(b*8+c)*NPTS + n];
  float* pre1 = ws + PRE1_OFF;

  float s1s[4]={0,0,0,0}, s1q[4]={0,0,0,0};
  float pv[8];
  #pragma unroll
  for(int c=0;c<8;c++){
    float v = b1[c];
    #pragma unroll
    for(int j=0;j<8;j++) v += W1[c*8+j]*f[j];
    pv[c]=v;
    s1s[c>>1]+=v; s1q[c>>1]+=v*v;
  }
  float4* pr = (float4*)(pre1 + p*8);
  pr[0] = make_float4(pv[0],pv[1],pv[2],pv[3]);
  pr[1] = make_float4(pv[4],pv[5],pv[6],pv[7]);

  float sss[4]={0,0,0,0}, ssq[4]={0,0,0,0};
  #pragma unroll
  for(int o=0;o<32;o++){
    float v = bs[o];
    #pragma unroll
    for(int j=0;j<8;j++) v += Ws[o*8+j]*f[j];
    sss[o>>3]+=v; ssq[o>>3]+=v*v;
  }
  const float4* xp = (const float4*)(ws + XYZP_OFF);
  float4 ct = xp[p];
  float l1s[4]={0,0,0,0}, l1q[4]={0,0,0,0};
  const int* nr = nidx + p*KNB;
  #pragma unroll
  for(int k=0;k<KNB;k++){
    int idx = nr[k];
    float4 nb = xp[(b<<LOGN)|idx];
    float rx=nb.x-ct.x, ry=nb.y-ct.y, rz=nb.z-ct.z;
    float dd = sqrtf(rx*rx+ry*ry+rz*rz);
    float fr[10] = {dd,rx,ry,rz,ct.x,ct.y,ct.z,nb.x,nb.y,nb.z};
    #pragma unroll
    for(int c=0;c<8;c++){
      float v = bl1[c];
      #pragma unroll
      for(int j=0;j<10;j++) v += WL1[c*10+j]*fr[j];
      l1s[c>>1]+=v; l1q[c>>1]+=v*v;
    }
  }
  __shared__ float lst[24];
  if(threadIdx.x < 24) lst[threadIdx.x] = 0.f;
  __syncthreads();
  int lane = threadIdx.x & 63;
  #pragma unroll
  for(int g=0; g<4; g++){
    float a1v = wred(s1s[g]), a2v = wred(s1q[g]);
    float d1v = wred(sss[g]), d2v = wred(ssq[g]);
    float e1v = wred(l1s[g]), e2v = wred(l1q[g]);
    if(lane==0){
      atomicAdd(&lst[ 0+g*2], a1v); atomicAdd(&lst[ 1+g*2], a2v);
      atomicAdd(&lst[ 8+g*2], d1v); atomicAdd(&lst[ 9+g*2], d2v);
      atomicAdd(&lst[16+g*2], e1v); atomicAdd(&lst[17+g*2], e2v);
    }
  }
  __syncthreads();
  if(threadIdx.x < 24){
    int stage = threadIdx.x >> 3;
    int g = (threadIdx.x >> 1) & 3;
    int w = threadIdx.x & 1;
    atomicAdd(ws + ((stage*4+b)*4+g)*128 + w*64 + (blockIdx.x&63), lst[threadIdx.x]);
  }
}

// ---------------- K2: att-pool 1 (MFMA scores, wave-local) ----------------
__global__ __launch_bounds__(256,6) void k2(
    const int* __restrict__ nidx,
    const float* __restrict__ WL1, const float* __restrict__ bl1,
    const float* __restrict__ Wa1,
    const float* __restrict__ Wm1, const float* __restrict__ bm1,
    const float* __restrict__ W2,  const float* __restrict__ b2,
    float* __restrict__ ws){
  const float* fin = ws + FIN_OFF;
  int b = blockIdx.y;
  int tid = threadIdx.x;
  int w = tid>>6, lane = tid&63, q = lane>>4, l15 = lane&15;
  int pg = q, kk = l15;                     // phase-A role: point pg, neighbor kk
  int n0 = blockIdx.x*16 + w*4 + pg;
  int p = (b<<LOGN) | n0;

  float scP[8], shP[8], scL[8], shL[8];
  #pragma unroll
  for(int c=0;c<8;c++){
    load_fin(fin, ST_MLP1,b,c, scP[c],shP[c]);
    load_fin(fin, ST_L1,  b,c, scL[c],shL[c]);
  }
  // A-frag: Wa1 row l15, contraction chunk q*8..q*8+7 (zeros for q>=2)
  U16 au; au.u = make_uint4(0,0,0,0);
  if(q < 2){
    const float* wr = Wa1 + l15*16 + q*8;
    float4 w0 = *(const float4*)(wr);
    float4 w1 = *(const float4*)(wr+4);
    au.u = make_uint4(pkbf(w0.x,w0.y), pkbf(w0.z,w0.w), pkbf(w1.x,w1.y), pkbf(w1.z,w1.w));
  }
  short8 afr = au.s;
  // Wm1 row (l15&7)
  float wmr[16];
  {
    const float4* wp = (const float4*)(Wm1 + (l15&7)*16);
    float4 m0=wp[0], m1=wp[1], m2=wp[2], m3=wp[3];
    wmr[0]=m0.x; wmr[1]=m0.y; wmr[2]=m0.z; wmr[3]=m0.w;
    wmr[4]=m1.x; wmr[5]=m1.y; wmr[6]=m1.z; wmr[7]=m1.w;
    wmr[8]=m2.x; wmr[9]=m2.y; wmr[10]=m2.z; wmr[11]=m2.w;
    wmr[12]=m3.x; wmr[13]=m3.y; wmr[14]=m3.z; wmr[15]=m3.w;
  }

  __shared__ unsigned char SB[4][WV_BYTES];
  __shared__ float lst[16];
  if(tid<16) lst[tid]=0.f;
  char* wb = (char*)SB[w];

  const float4* xp = (const float4*)(ws + XYZP_OFF);
  const float* pre1 = ws + PRE1_OFF;
  float* prem1 = ws + PREM1_OFF;

  // ---- phase A: per-lane column (pg, kk) ----
  int idx = nidx[p*KNB + kk];
  int pi = (b<<LOGN) | idx;
  float4 nb = xp[pi], ct = xp[p];
  float rx=nb.x-ct.x, ry=nb.y-ct.y, rz=nb.z-ct.z;
  float dd = sqrtf(rx*rx+ry*ry+rz*rz);
  float fr[10] = {dd,rx,ry,rz,ct.x,ct.y,ct.z,nb.x,nb.y,nb.z};
  float fx[8];
  #pragma unroll
  for(int c=0;c<8;c++){
    float v = bl1[c];
    #pragma unroll
    for(int j=0;j<10;j++) v += WL1[c*10+j]*fr[j];
    fx[c] = lrelu(v*scL[c]+shL[c]);
  }
  float xn[8];
  const float4* pr = (const float4*)(pre1 + pi*8);
  float4 a0=pr[0], a1=pr[1];
  xn[0]=lrelu(a0.x*scP[0]+shP[0]); xn[1]=lrelu(a0.y*scP[1]+shP[1]);
  xn[2]=lrelu(a0.z*scP[2]+shP[2]); xn[3]=lrelu(a0.w*scP[3]+shP[3]);
  xn[4]=lrelu(a1.x*scP[4]+shP[4]); xn[5]=lrelu(a1.y*scP[5]+shP[5]);
  xn[6]=lrelu(a1.z*scP[6]+shP[6]); xn[7]=lrelu(a1.w*scP[7]+shP[7]);

  unsigned d[8];
  d[0]=pkbf(xn[0],xn[1]); d[1]=pkbf(xn[2],xn[3]); d[2]=pkbf(xn[4],xn[5]); d[3]=pkbf(xn[6],xn[7]);
  d[4]=pkbf(fx[0],fx[1]); d[5]=pkbf(fx[2],fx[3]); d[6]=pkbf(fx[4],fx[5]); d[7]=pkbf(fx[6],fx[7]);
  // xbuf B-frag planes (dense)
  *(uint4*)(wb + XB_OFF +        (pg*16+kk)*16) = make_uint4(d[0],d[1],d[2],d[3]);
  *(uint4*)(wb + XB_OFF + 1024 + (pg*16+kk)*16) = make_uint4(d[4],d[5],d[6],d[7]);
  // xrow: [pg][o][kk] bf16
  #pragma unroll
  for(int c2=0;c2<8;c2++){
    *(short*)(wb + XR_OFF + pg*512 + (2*c2  )*32 + kk*2) = (short)(d[c2] & 0xffff);
    *(short*)(wb + XR_OFF + pg*512 + (2*c2+1)*32 + kk*2) = (short)(d[c2] >> 16);
  }

  wave_fence();

  // ---- phase B: 4 MFMAs (one per point) ----
  f32x4 cz = {0.f,0.f,0.f,0.f};
  U16 bu0,bu1,bu2,bu3;
  bu0.u = *(uint4*)(wb + XB_OFF + (q&1)*1024 + (0*16+l15)*16);
  bu1.u = *(uint4*)(wb + XB_OFF + (q&1)*1024 + (1*16+l15)*16);
  bu2.u = *(uint4*)(wb + XB_OFF + (q&1)*1024 + (2*16+l15)*16);
  bu3.u = *(uint4*)(wb + XB_OFF + (q&1)*1024 + (3*16+l15)*16);
  f32x4 c0 = __builtin_amdgcn_mfma_f32_16x16x32_bf16(afr, bu0.s, cz, 0,0,0);
  f32x4 c1 = __builtin_amdgcn_mfma_f32_16x16x32_bf16(afr, bu1.s, cz, 0,0,0);
  f32x4 c2f = __builtin_amdgcn_mfma_f32_16x16x32_bf16(afr, bu2.s, cz, 0,0,0);
  f32x4 c3 = __builtin_amdgcn_mfma_f32_16x16x32_bf16(afr, bu3.s, cz, 0,0,0);
  // scatter C rows (4q+r, col l15) to ssp as bf16
  #pragma unroll
  for(int pp=0; pp<4; pp++){
    f32x4 cf = (pp==0)?c0:(pp==1)?c1:(pp==2)?c2f:c3;
    unsigned e0 = pkbf(cf[0], cf[1]);
    unsigned e1 = pkbf(cf[2], cf[3]);
    char* base = wb + SS_OFF + pp*512 + l15*2;
    *(short*)(base + (4*q+0)*32) = (short)(e0 & 0xffff);
    *(short*)(base + (4*q+1)*32) = (short)(e0 >> 16);
    *(short*)(base + (4*q+2)*32) = (short)(e1 & 0xffff);
    *(short*)(base + (4*q+3)*32) = (short)(e1 >> 16);
  }

  wave_fence();

  // ---- phase C: row role (pg, o=l15) ----
  int o = l15;
  uint4 srow0 = *(uint4*)(wb + SS_OFF + pg*512 + o*32);
  uint4 srow1 = *(uint4*)(wb + SS_OFF + pg*512 + o*32 + 16);
  float sr[16];
  sr[0]=blo(srow0.x); sr[1]=bhi(srow0.x); sr[2]=blo(srow0.y); sr[3]=bhi(srow0.y);
  sr[4]=blo(srow0.z); sr[5]=bhi(srow0.z); sr[6]=blo(srow0.w); sr[7]=bhi(srow0.w);
  sr[8]=blo(srow1.x); sr[9]=bhi(srow1.x); sr[10]=blo(srow1.y); sr[11]=bhi(srow1.y);
  sr[12]=blo(srow1.z); sr[13]=bhi(srow1.z); sr[14]=blo(srow1.w); sr[15]=bhi(srow1.w);
  float mx=sr[0];
  #pragma unroll
  for(int k=1;k<16;k++) mx=fmaxf(mx,sr[k]);
  float pe[16]; float sum=0.f;
  #pragma unroll
  for(int k=0;k<16;k++){ pe[k]=__expf(sr[k]-mx); sum+=pe[k]; }
  uint4 xrow0 = *(uint4*)(wb + XR_OFF + pg*512 + o*32);
  uint4 xrow1 = *(uint4*)(wb + XR_OFF + pg*512 + o*32 + 16);
  float xr[16];
  xr[0]=blo(xrow0.x); xr[1]=bhi(xrow0.x); xr[2]=blo(xrow0.y); xr[3]=bhi(xrow0.y);
  xr[4]=blo(xrow0.z); xr[5]=bhi(xrow0.z); xr[6]=blo(xrow0.w); xr[7]=bhi(xrow0.w);
  xr[8]=blo(xrow1.x); xr[9]=bhi(xrow1.x); xr[10]=blo(xrow1.y); xr[11]=bhi(xrow1.y);
  xr[12]=blo(xrow1.z); xr[13]=bhi(xrow1.z); xr[14]=blo(xrow1.w); xr[15]=bhi(xrow1.w);
  float acc=0.f;
  #pragma unroll
  for(int k=0;k<16;k++) acc += pe[k]*xr[k];
  float agg = acc/sum;
  *(float*)(wb + AG_OFF + pg*68 + o*4) = agg;

  // lfa2 pre-GN stats from own column fx (phase-A role values)
  float l2s[4]={0,0,0,0}, l2q[4]={0,0,0,0};
  #pragma unroll
  for(int c=0;c<8;c++){
    float v = b2[c];
    #pragma unroll
    for(int j=0;j<8;j++) v += W2[c*8+j]*fx[j];
    l2s[c>>1]+=v; l2q[c>>1]+=v*v;
  }

  wave_fence();

  float m1v=0.f;
  bool doM1 = (o<8);
  if(doM1){
    const float* agp = (const float*)(wb + AG_OFF + pg*68);
    float v = bm1[o];
    #pragma unroll
    for(int j=0;j<16;j++) v += wmr[j]*agp[j];
    prem1[p*8+o]=v;
    m1v=v;
  }

  __syncthreads();
  #pragma unroll
  for(int g=0;g<4;g++){
    float a=wred(l2s[g]), qq=wred(l2q[g]);
    if(lane==0){ atomicAdd(&lst[g*2],a); atomicAdd(&lst[g*2+1],qq); }
  }
  if(doM1){
    atomicAdd(&lst[8+(o>>1)*2],   m1v);
    atomicAdd(&lst[8+(o>>1)*2+1], m1v*m1v);
  }
  __syncthreads();
  if(tid<16){
    int half=tid>>3, g=(tid>>1)&3, wsel=tid&1;
    int stage = half? ST_M1 : ST_L2;
    atomicAdd(ws + ((stage*4+b)*4+g)*128 + wsel*64 + (blockIdx.x&63), lst[tid]);
  }
}

// ---------------- K3: att-pool 2 (MFMA scores, wave-local) ----------------
__global__ __launch_bounds__(256,6) void k3(
    const int* __restrict__ nidx,
    const float* __restrict__ WL1, const float* __restrict__ bl1,
    const float* __restrict__ W2,  const float* __restrict__ b2,
    const float* __restrict__ Wa2,
    const float* __restrict__ Wm2, const float* __restrict__ bm2,
    float* __restrict__ ws){
  const float* fin = ws + FIN_OFF;
  int b = blockIdx.y;
  int tid = threadIdx.x;
  int w = tid>>6, lane = tid&63, q = lane>>4, l15 = lane&15;
  int pg = q, kk = l15;
  int n0 = blockIdx.x*16 + w*4 + pg;
  int p = (b<<LOGN) | n0;

  float scL[8], shL[8], scL2[8], shL2[8], scM[8], shM[8];
  #pragma unroll
  for(int c=0;c<8;c++){
    load_fin(fin, ST_L1, b,c, scL[c], shL[c]);
    load_fin(fin, ST_L2, b,c, scL2[c],shL2[c]);
    load_fin(fin, ST_M1, b,c, scM[c], shM[c]);
  }
  U16 au; au.u = make_uint4(0,0,0,0);
  if(q < 2){
    const float* wr = Wa2 + l15*16 + q*8;
    float4 w0 = *(const float4*)(wr);
    float4 w1 = *(const float4*)(wr+4);
    au.u = make_uint4(pkbf(w0.x,w0.y), pkbf(w0.z,w0.w), pkbf(w1.x,w1.y), pkbf(w1.z,w1.w));
  }
  short8 afr = au.s;
  float wmr[16];
  {
    const float4* wp = (const float4*)(Wm2 + l15*16);
    float4 m0=wp[0], m1=wp[1], m2=wp[2], m3=wp[3];
    wmr[0]=m0.x; wmr[1]=m0.y; wmr[2]=m0.z; wmr[3]=m0.w;
    wmr[4]=m1.x; wmr[5]=m1.y; wmr[6]=m1.z; wmr[7]=m1.w;
    wmr[8]=m2.x; wmr[9]=m2.y; wmr[10]=m2.z; wmr[11]=m2.w;
    wmr[12]=m3.x; wmr[13]=m3.y; wmr[14]=m3.z; wmr[15]=m3.w;
  }

  __shared__ unsigned char SB[4][WV_BYTES];
  __shared__ float lst[8];
  if(tid<8) lst[tid]=0.f;
  char* wb = (char*)SB[w];

  const float4* xp = (const float4*)(ws + XYZP_OFF);
  const float* prem1 = ws + PREM1_OFF;
  float* prem2 = ws + PREM2_OFF;

  // ---- phase A ----
  int idx = nidx[p*KNB + kk];
  int pi = (b<<LOGN) | idx;
  float4 nb = xp[pi], ct = xp[p];
  float rx=nb.x-ct.x, ry=nb.y-ct.y, rz=nb.z-ct.z;
  float dd = sqrtf(rx*rx+ry*ry+rz*rz);
  float fr[10] = {dd,rx,ry,rz,ct.x,ct.y,ct.z,nb.x,nb.y,nb.z};
  float fx[8];
  #pragma unroll
  for(int c=0;c<8;c++){
    float v = bl1[c];
    #pragma unroll
    for(int j=0;j<10;j++) v += WL1[c*10+j]*fr[j];
    fx[c] = lrelu(v*scL[c]+shL[c]);
  }
  float fx2[8];
  #pragma unroll
  for(int c=0;c<8;c++){
    float v = b2[c];
    #pragma unroll
    for(int j=0;j<8;j++) v += W2[c*8+j]*fx[j];
    fx2[c] = lrelu(v*scL2[c]+shL2[c]);
  }
  float xn[8];
  const float4* prr = (const float4*)(prem1 + pi*8);
  float4 a0=prr[0], a1=prr[1];
  xn[0]=lrelu(a0.x*scM[0]+shM[0]); xn[1]=lrelu(a0.y*scM[1]+shM[1]);
  xn[2]=lrelu(a0.z*scM[2]+shM[2]); xn[3]=lrelu(a0.w*scM[3]+shM[3]);
  xn[4]=lrelu(a1.x*scM[4]+shM[4]); xn[5]=lrelu(a1.y*scM[5]+shM[5]);
  xn[6]=lrelu(a1.z*scM[6]+shM[6]); xn[7]=lrelu(a1.w*scM[7]+shM[7]);

  unsigned d[8];
  d[0]=pkbf(xn[0],xn[1]); d[1]=pkbf(xn[2],xn[3]); d[2]=pkbf(xn[4],xn[5]); d[3]=pkbf(xn[6],xn[7]);
  d[4]=pkbf(fx2[0],fx2[1]); d[5]=pkbf(fx2[2],fx2[3]); d[6]=pkbf(fx2[4],fx2[5]); d[7]=pkbf(fx2[6],fx2[7]);
  *(uint4*)(wb + XB_OFF +        (pg*16+kk)*16) = make_uint4(d[0],d[1],d[2],d[3]);
  *(uint4*)(wb + XB_OFF + 1024 + (pg*16+kk)*16) = make_uint4(d[4],d[5],d[6],d[7]);
  #pragma unroll
  for(int c2=0;c2<8;c2++){
    *(short*)(wb + XR_OFF + pg*512 + (2*c2  )*32 + kk*2) = (short)(d[c2] & 0xffff);
    *(short*)(wb + XR_OFF + pg*512 + (2*c2+1)*32 + kk*2) = (short)(d[c2] >> 16);
  }

  wave_fence();

  f32x4 cz = {0.f,0.f,0.f,0.f};
  U16 bu0,bu1,bu2,bu3;
  bu0.u = *(uint4*)(wb + XB_OFF + (q&1)*1024 + (0*16+l15)*16);
  bu1.u = *(uint4*)(wb + XB_OFF + (q&1)*1024 + (1*16+l15)*16);
  bu2.u = *(uint4*)(wb + XB_OFF + (q&1)*1024 + (2*16+l15)*16);
  bu3.u = *(uint4*)(wb + XB_OFF + (q&1)*1024 + (3*16+l15)*16);
  f32x4 c0 = __builtin_amdgcn_mfma_f32_16x16x32_bf16(afr, bu0.s, cz, 0,0,0);
  f32x4 c1 = __builtin_amdgcn_mfma_f32_16x16x32_bf16(afr, bu1.s, cz, 0,0,0);
  f32x4 c2f = __builtin_amdgcn_mfma_f32_16x16x32_bf16(afr, bu2.s, cz, 0,0,0);
  f32x4 c3 = __builtin_amdgcn_mfma_f32_16x16x32_bf16(afr, bu3.s, cz, 0,0,0);
  #pragma unroll
  for(int pp=0; pp<4; pp++){
    f32x4 cf = (pp==0)?c0:(pp==1)?c1:(pp==2)?c2f:c3;
    unsigned e0 = pkbf(cf[0], cf[1]);
    unsigned e1 = pkbf(cf[2], cf[3]);
    char* base = wb + SS_OFF + pp*512 + l15*2;
    *(short*)(base + (4*q+0)*32) = (short)(e0 & 0xffff);
    *(short*)(base + (4*q+1)*32) = (short)(e0 >> 16);
    *(short*)(base + (4*q+2)*32) = (short)(e1 & 0xffff);
    *(short*)(base + (4*q+3)*32) = (short)(e1 >> 16);
  }

  wave_fence();

  int o = l15;
  uint4 srow0 = *(uint4*)(wb + SS_OFF + pg*512 + o*32);
  uint4 srow1 = *(uint4*)(wb + SS_OFF + pg*512 + o*32 + 16);
  float sr[16];
  sr[0]=blo(srow0.x); sr[1]=bhi(srow0.x); sr[2]=blo(srow0.y); sr[3]=bhi(srow0.y);
  sr[4]=blo(srow0.z); sr[5]=bhi(srow0.z); sr[6]=blo(srow0.w); sr[7]=bhi(srow0.w);
  sr[8]=blo(srow1.x); sr[9]=bhi(srow1.x); sr[10]=blo(srow1.y); sr[11]=bhi(srow1.y);
  sr[12]=blo(srow1.z); sr[13]=bhi(srow1.z); sr[14]=blo(srow1.w); sr[15]=bhi(srow1.w);
  float mx=sr[0];
  #pragma unroll
  for(int k=1;k<16;k++) mx=fmaxf(mx,sr[k]);
  float pe[16]; float sum=0.f;
  #pragma unroll
  for(int k=0;k<16;k++){ pe[k]=__expf(sr[k]-mx); sum+=pe[k]; }
  uint4 xrow0 = *(uint4*)(wb + XR_OFF + pg*512 + o*32);
  uint4 xrow1 = *(uint4*)(wb + XR_OFF + pg*512 + o*32 + 16);
  float xr[16];
  xr[0]=blo(xrow0.x); xr[1]=bhi(xrow0.x); xr[2]=blo(xrow0.y); xr[3]=bhi(xrow0.y);
  xr[4]=blo(xrow0.z); xr[5]=bhi(xrow0.z); xr[6]=blo(xrow0.w); xr[7]=bhi(xrow0.w);
  xr[8]=blo(xrow1.x); xr[9]=bhi(xrow1.x); xr[10]=blo(xrow1.y); xr[11]=bhi(xrow1.y);
  xr[12]=blo(xrow1.z); xr[13]=bhi(xrow1.z); xr[14]=blo(xrow1.w); xr[15]=bhi(xrow1.w);
  float acc=0.f;
  #pragma unroll
  for(int k=0;k<16;k++) acc += pe[k]*xr[k];
  float agg = acc/sum;
  *(float*)(wb + AG_OFF + pg*68 + o*4) = agg;

  wave_fence();

  const float* agp = (const float*)(wb + AG_OFF + pg*68);
  float v = bm2[o];
  #pragma unroll
  for(int j=0;j<16;j++) v += wmr[j]*agp[j];
  prem2[p*16+o]=v;

  __syncthreads();
  atomicAdd(&lst[(o>>2)*2],   v);
  atomicAdd(&lst[(o>>2)*2+1], v*v);
  __syncthreads();
  if(tid<8){
    int g=(tid>>1)&3, wsel=tid&1;
    atomicAdd(ws + ((ST_M2*4+b)*4+g)*128 + wsel*64 + (blockIdx.x&63), lst[tid]);
  }
}

// ---------------- K4: stats of mlp2 output ----------------
__global__ __launch_bounds__(256) void k4(
    const float* __restrict__ Wo,  const float* __restrict__ bo,
    float* __restrict__ ws){
  const float* fin = ws + FIN_OFF;
  int b=blockIdx.y; int n=blockIdx.x*256+threadIdx.x; int p=(b<<LOGN)|n;
  float scM[16], shM[16];
  #pragma unroll
  for(int c=0;c<16;c++) load_fin(fin, ST_M2, b, c, scM[c], shM[c]);
  const float4* pm = (const float4*)(ws + PREM2_OFF) + p*4;
  float fa[16];
  #pragma unroll
  for(int i=0;i<4;i++){
    float4 v4 = pm[i];
    fa[i*4+0]=lrelu(v4.x*scM[i*4+0]+shM[i*4+0]);
    fa[i*4+1]=lrelu(v4.y*scM[i*4+1]+shM[i*4+1]);
    fa[i*4+2]=lrelu(v4.z*scM[i*4+2]+shM[i*4+2]);
    fa[i*4+3]=lrelu(v4.w*scM[i*4+3]+shM[i*4+3]);
  }
  float sos[4]={0,0,0,0}, soq[4]={0,0,0,0};
  #pragma unroll
  for(int o=0;o<32;o++){
    float v=bo[o];
    #pragma unroll
    for(int c=0;c<16;c++) v += Wo[o*16+c]*fa[c];
    sos[o>>3]+=v; soq[o>>3]+=v*v;
  }
  __shared__ float lst[8];
  if(threadIdx.x<8) lst[threadIdx.x]=0.f;
  __syncthreads();
  int lane = threadIdx.x & 63;
  #pragma unroll
  for(int g=0;g<4;g++){
    float a=wred(sos[g]), q=wred(soq[g]);
    if(lane==0){ atomicAdd(&lst[g*2],a); atomicAdd(&lst[g*2+1],q); }
  }
  __syncthreads();
  if(threadIdx.x<8){
    int g=(threadIdx.x>>1)&3, w=threadIdx.x&1;
    atomicAdd(ws + ((ST_OUT*4+b)*4+g)*128 + w*64 + (blockIdx.x&63), lst[threadIdx.x]);
  }
}

// ---------------- K5: final out ----------------
__global__ __launch_bounds__(256) void k5(
    const float* __restrict__ feat,
    const float* __restrict__ Wo,  const float* __restrict__ bo,
    const float* __restrict__ Wsk, const float* __restrict__ bsk,
    const float* __restrict__ ws, float* __restrict__ out){
  const float* fin = ws + FIN_OFF;
  int b=blockIdx.y; int n=blockIdx.x*256+threadIdx.x; int p=(b<<LOGN)|n;
  float scM[16], shM[16];
  #pragma unroll
  for(int c=0;c<16;c++) load_fin(fin, ST_M2, b, c, scM[c], shM[c]);
  const float4* pm = (const float4*)(ws + PREM2_OFF) + p*4;
  float fa[16];
  #pragma unroll
  for(int i=0;i<4;i++){
    float4 v4 = pm[i];
    fa[i*4+0]=lrelu(v4.x*scM[i*4+0]+shM[i*4+0]);
    fa[i*4+1]=lrelu(v4.y*scM[i*4+1]+shM[i*4+1]);
    fa[i*4+2]=lrelu(v4.z*scM[i*4+2]+shM[i*4+2]);
    fa[i*4+3]=lrelu(v4.w*scM[i*4+3]+shM[i*4+3]);
  }
  float f[8];
  #pragma unroll
  for(int c=0;c<8;c++) f[c]=feat[(b*8+c)*NPTS+n];
  #pragma unroll
  for(int o=0;o<32;o++){
    float to = bo[o];
    #pragma unroll
    for(int c=0;c<16;c++) to += Wo[o*16+c]*fa[c];
    float ts = bsk[o];
    #pragma unroll
    for(int j=0;j<8;j++) ts += Wsk[o*8+j]*f[j];
    float scO, shO, scS, shS;
    load_fin(fin, ST_OUT,  b, o, scO, shO);
    load_fin(fin, ST_SKIP, b, o, scS, shS);
    float v = to*scO+shO + ts*scS+shS;
    out[(b*32+o)*NPTS + n] = lrelu(v);
  }
}

extern "C" void kernel_launch(void* const* d_in, const int* in_sizes, int n_in,
                              void* d_out, int out_size, void* d_ws, size_t ws_size,
                              hipStream_t stream){
  (void)in_sizes; (void)n_in; (void)out_size; (void)ws_size;
  const float* feat=(const float*)d_in[0];
  const float* xyz =(const float*)d_in[1];
  const int*   nidx=(const int*)d_in[2];
  const float* W1  =(const float*)d_in[3];
  const float* b1  =(const float*)d_in[4];
  const float* g1  =(const float*)d_in[5];
  const float* be1 =(const float*)d_in[6];
  const float* WL1 =(const float*)d_in[7];
  const float* bl1 =(const float*)d_in[8];
  const float* gL1 =(const float*)d_in[9];
  const float* beL1=(const float*)d_in[10];
  const float* Wa1 =(const float*)d_in[11];
  const float* Wm1 =(const float*)d_in[12];
  const float* bm1 =(const float*)d_in[13];
  const float* gm1 =(const float*)d_in[14];
  const float* bem1=(const float*)d_in[15];
  const float* W2  =(const float*)d_in[16];
  const float* b2  =(const float*)d_in[17];
  const float* gL2 =(const float*)d_in[18];
  const float* beL2=(const float*)d_in[19];
  const float* Wa2 =(const float*)d_in[20];
  const float* Wm2 =(const float*)d_in[21];
  const float* bm2 =(const float*)d_in[22];
  const float* gm2 =(const float*)d_in[23];
  const float* bem2=(const float*)d_in[24];
  const float* Wo  =(const float*)d_in[25];
  const float* bo  =(const float*)d_in[26];
  const float* go  =(const float*)d_in[27];
  const float* beo =(const float*)d_in[28];
  const float* Wsk =(const float*)d_in[29];
  const float* bsk =(const float*)d_in[30];
  const float* gsk =(const float*)d_in[31];
  const float* besk=(const float*)d_in[32];
  float* ws=(float*)d_ws;
  float* out=(float*)d_out;

  hipMemsetAsync(d_ws, 0, STAT_F*sizeof(float), stream);
  k_pack<<<dim3(1024),dim3(256),0,stream>>>(xyz, ws);
  k1<<<dim3(256,4),dim3(256),0,stream>>>(feat, nidx, W1,b1, Wsk,bsk, WL1,bl1, ws);
  kfA<<<dim3(3),dim3(128),0,stream>>>(ws, g1,be1, gL1,beL1, gsk,besk);
  k2<<<dim3(4096,4),dim3(256),0,stream>>>(nidx, WL1,bl1, Wa1, Wm1,bm1, W2,b2, ws);
  kfB<<<dim3(2),dim3(128),0,stream>>>(ws, gm1,bem1, gL2,beL2);
  k3<<<dim3(4096,4),dim3(256),0,stream>>>(nidx, WL1,bl1, W2,b2, Wa2, Wm2,bm2, ws);
  kfC<<<dim3(1),dim3(128),0,stream>>>(ws, gm2,bem2);
  k4<<<dim3(256,4),dim3(256),0,stream>>>(Wo,bo, ws);
  kfD<<<dim3(1),dim3(128),0,stream>>>(ws, go,beo);
  k5<<<dim3(256,4),dim3(256),0,stream>>>(feat, Wo,bo, Wsk,bsk, ws, out);
}

// Round 4
// 316.069 us; speedup vs baseline: 3.2000x; 1.0089x over previous
//
#include <hip/hip_runtime.h>
#include <hip/hip_bf16.h>

#define NPTS 65536
#define LOGN 16
#define KNB 16
#define NEGS 0.2f
#define EPSV 1e-5f

// GN stages
#define ST_MLP1 0
#define ST_SKIP 1
#define ST_L1   2
#define ST_M1   3
#define ST_L2   4
#define ST_M2   5
#define ST_OUT  6

// ws layout (floats): raw stats | finalized (scale,shift) | xyz packed | pre1(bf16) | prem1(bf16) | prem2(f32)
#define STAT_F   14336                       // 7*4*4*128
#define FIN_OFF  14336
#define XYZP_OFF 16384
#define PRE1_OFF  (XYZP_OFF + 4*NPTS*4)      // bf16: 16B/point (4 floats worth)
#define PREM1_OFF (PRE1_OFF + 4*NPTS*4)      // bf16: 16B/point
#define PREM2_OFF (PREM1_OFF + 4*NPTS*4)     // f32: 16 ch/point

typedef __attribute__((ext_vector_type(8))) short short8;
typedef __attribute__((ext_vector_type(4))) float f32x4;

union U16 { uint4 u; short8 s; };

__device__ __forceinline__ float lrelu(float v){ return fmaxf(v, v*NEGS); }

__device__ __forceinline__ float wred(float v){
  #pragma unroll
  for(int off=32; off>0; off>>=1) v += __shfl_xor(v, off, 64);
  return v;
}

__device__ __forceinline__ void wave_fence(){
  __builtin_amdgcn_sched_barrier(0);
  asm volatile("s_waitcnt lgkmcnt(0)" ::: "memory");
  __builtin_amdgcn_sched_barrier(0);
}

__device__ __forceinline__ void load_fin(const float* fin, int stage, int b, int c,
                                         float& sc, float& sh){
  const float* fp = fin + ((stage*4+b)*32 + c)*2;
  sc = fp[0]; sh = fp[1];
}

__device__ __forceinline__ unsigned pkbf(float a, float b){
  __hip_bfloat162 h = __float22bfloat162_rn(make_float2(a,b));
  union{ __hip_bfloat162 h2; unsigned u; } cv; cv.h2 = h; return cv.u;
}
__device__ __forceinline__ float blo(unsigned d){ return __builtin_bit_cast(float, d<<16); }
__device__ __forceinline__ float bhi(unsigned d){ return __builtin_bit_cast(float, d & 0xffff0000u); }
__device__ __forceinline__ float bfu(unsigned short h){ return __builtin_bit_cast(float, ((unsigned)h)<<16); }

// per-wave LDS region: XB planes (2 x 1024B) + AG (256B)
#define XB_OFF 0
#define AG_OFF 2048
#define WV_BYTES 2304

// ---------------- K0: pack xyz -> float4 [b][n] ----------------
__global__ __launch_bounds__(256) void k_pack(const float* __restrict__ xyz,
                                              float* __restrict__ ws){
  int p = blockIdx.x*256 + threadIdx.x;
  int b = p >> LOGN, n = p & (NPTS-1);
  const float* xb = xyz + b*3*NPTS + n;
  float4 v = make_float4(xb[0], xb[NPTS], xb[2*NPTS], 0.f);
  ((float4*)(ws + XYZP_OFF))[p] = v;
}

// ---------------- fin: raw slots -> (scale,shift) per channel ----------------
__device__ void fin_stage(const float* __restrict__ ws, float* __restrict__ fin,
                          int stage, int nch, float cnt,
                          const float* __restrict__ gamma, const float* __restrict__ beta){
  int t = threadIdx.x;
  if(t >= 4*nch) return;
  int b = t / nch, c = t - b*nch;
  int g = c / (nch/4);
  const float* sl = ws + ((stage*4+b)*4+g)*128;
  float s=0.f, q=0.f;
  #pragma unroll 8
  for(int i=0;i<64;i++){ s += sl[i]; q += sl[64+i]; }
  float mean = s/cnt;
  float var  = q/cnt - mean*mean;
  float inv  = rsqrtf(var + EPSV);
  float sc = inv*gamma[c];
  float sh = beta[c] - mean*sc;
  float* fp = fin + ((stage*4+b)*32 + c)*2;
  fp[0]=sc; fp[1]=sh;
}

__global__ __launch_bounds__(128) void kfA(float* __restrict__ ws,
    const float* g1, const float* be1, const float* gL1, const float* beL1,
    const float* gsk, const float* besk){
  if(blockIdx.x==0)      fin_stage(ws, ws+FIN_OFF, ST_MLP1, 8,  2.0f*NPTS,      g1, be1);
  else if(blockIdx.x==1) fin_stage(ws, ws+FIN_OFF, ST_L1,   8,  2.0f*NPTS*KNB,  gL1, beL1);
  else                   fin_stage(ws, ws+FIN_OFF, ST_SKIP, 32, 8.0f*NPTS,      gsk, besk);
}
__global__ __launch_bounds__(128) void kfB(float* __restrict__ ws,
    const float* gm1, const float* bem1, const float* gL2, const float* beL2){
  if(blockIdx.x==0) fin_stage(ws, ws+FIN_OFF, ST_M1, 8, 2.0f*NPTS,     gm1, bem1);
  else              fin_stage(ws, ws+FIN_OFF, ST_L2, 8, 2.0f*NPTS*KNB, gL2, beL2);
}
__global__ __launch_bounds__(128) void kfC(float* __restrict__ ws,
    const float* gm2, const float* bem2){
  fin_stage(ws, ws+FIN_OFF, ST_M2, 16, 4.0f*NPTS, gm2, bem2);
}
__global__ __launch_bounds__(128) void kfD(float* __restrict__ ws,
    const float* go, const float* beo){
  fin_stage(ws, ws+FIN_OFF, ST_OUT, 32, 8.0f*NPTS, go, beo);
}

// ---------------- K1: mlp1 pre(bf16) + stats; skip stats; lfa1 stats ----------------
__global__ __launch_bounds__(256) void k1(
    const float* __restrict__ feat, const int* __restrict__ nidx,
    const float* __restrict__ W1,  const float* __restrict__ b1,
    const float* __restrict__ Ws,  const float* __restrict__ bs,
    const float* __restrict__ WL1, const float* __restrict__ bl1,
    float* __restrict__ ws){
  int b = blockIdx.y;
  int n = blockIdx.x*256 + threadIdx.x;
  int p = (b<<LOGN) | n;
  float f[8];
  #pragma unroll
  for(int c=0;c<8;c++) f[c] = feat[(b*8+c)*NPTS + n];

  float s1s[4]={0,0,0,0}, s1q[4]={0,0,0,0};
  float pv[8];
  #pragma unroll
  for(int c=0;c<8;c++){
    float v = b1[c];
    #pragma unroll
    for(int j=0;j<8;j++) v += W1[c*8+j]*f[j];
    pv[c]=v;
    s1s[c>>1]+=v; s1q[c>>1]+=v*v;
  }
  uint4 pk = make_uint4(pkbf(pv[0],pv[1]), pkbf(pv[2],pv[3]),
                        pkbf(pv[4],pv[5]), pkbf(pv[6],pv[7]));
  *(uint4*)((char*)(ws + PRE1_OFF) + (size_t)p*16) = pk;

  float sss[4]={0,0,0,0}, ssq[4]={0,0,0,0};
  #pragma unroll
  for(int o=0;o<32;o++){
    float v = bs[o];
    #pragma unroll
    for(int j=0;j<8;j++) v += Ws[o*8+j]*f[j];
    sss[o>>3]+=v; ssq[o>>3]+=v*v;
  }
  const float4* xp = (const float4*)(ws + XYZP_OFF);
  float4 ct = xp[p];
  float l1s[4]={0,0,0,0}, l1q[4]={0,0,0,0};
  const int* nr = nidx + p*KNB;
  #pragma unroll
  for(int k=0;k<KNB;k++){
    int idx = nr[k];
    float4 nb = xp[(b<<LOGN)|idx];
    float rx=nb.x-ct.x, ry=nb.y-ct.y, rz=nb.z-ct.z;
    float dd = sqrtf(rx*rx+ry*ry+rz*rz);
    float fr[10] = {dd,rx,ry,rz,ct.x,ct.y,ct.z,nb.x,nb.y,nb.z};
    #pragma unroll
    for(int c=0;c<8;c++){
      float v = bl1[c];
      #pragma unroll
      for(int j=0;j<10;j++) v += WL1[c*10+j]*fr[j];
      l1s[c>>1]+=v; l1q[c>>1]+=v*v;
    }
  }
  __shared__ float lst[24];
  if(threadIdx.x < 24) lst[threadIdx.x] = 0.f;
  __syncthreads();
  int lane = threadIdx.x & 63;
  #pragma unroll
  for(int g=0; g<4; g++){
    float a1v = wred(s1s[g]), a2v = wred(s1q[g]);
    float d1v = wred(sss[g]), d2v = wred(ssq[g]);
    float e1v = wred(l1s[g]), e2v = wred(l1q[g]);
    if(lane==0){
      atomicAdd(&lst[ 0+g*2], a1v); atomicAdd(&lst[ 1+g*2], a2v);
      atomicAdd(&lst[ 8+g*2], d1v); atomicAdd(&lst[ 9+g*2], d2v);
      atomicAdd(&lst[16+g*2], e1v); atomicAdd(&lst[17+g*2], e2v);
    }
  }
  __syncthreads();
  if(threadIdx.x < 24){
    int stage = threadIdx.x >> 3;
    int g = (threadIdx.x >> 1) & 3;
    int w = threadIdx.x & 1;
    atomicAdd(ws + ((stage*4+b)*4+g)*128 + w*64 + (blockIdx.x&63), lst[threadIdx.x]);
  }
}

// ---------------- K2: att-pool 1, S^T MFMA, register softmax ----------------
__global__ __launch_bounds__(256,6) void k2(
    const int* __restrict__ nidx,
    const float* __restrict__ WL1, const float* __restrict__ bl1,
    const float* __restrict__ Wa1,
    const float* __restrict__ Wm1, const float* __restrict__ bm1,
    const float* __restrict__ W2,  const float* __restrict__ b2,
    float* __restrict__ ws){
  const float* fin = ws + FIN_OFF;
  int b = blockIdx.y;
  int tid = threadIdx.x;
  int w = tid>>6, lane = tid&63, q = lane>>4, l15 = lane&15;
  int nbase = blockIdx.x*16 + w*4;
  int pA = (b<<LOGN) | (nbase + q);          // phase-A point (pg = q)

  float scP[8], shP[8], scL[8], shL[8];
  #pragma unroll
  for(int c=0;c<8;c++){
    load_fin(fin, ST_MLP1,b,c, scP[c],shP[c]);
    load_fin(fin, ST_L1,  b,c, scL[c],shL[c]);
  }
  // B-frag: Wa^T -> lane(q,l15): B[q*8+j][l15] = Wa1[l15][q*8+j]; zero for q>=2
  U16 bu; bu.u = make_uint4(0,0,0,0);
  if(q < 2){
    const float* wr = Wa1 + l15*16 + q*8;
    float4 w0 = *(const float4*)(wr);
    float4 w1 = *(const float4*)(wr+4);
    bu.u = make_uint4(pkbf(w0.x,w0.y), pkbf(w0.z,w0.w), pkbf(w1.x,w1.y), pkbf(w1.z,w1.w));
  }

  __shared__ unsigned char SB[4][WV_BYTES];
  __shared__ float lst[16];
  if(tid<16) lst[tid]=0.f;
  char* wb = (char*)SB[w];

  const float4* xp = (const float4*)(ws + XYZP_OFF);
  const char* pre1b = (const char*)(ws + PRE1_OFF);
  char* prem1b = (char*)(ws + PREM1_OFF);

  // ---- phase A: lane = (point q, neighbor l15) ----
  int idx = nidx[pA*KNB + l15];
  int pi = (b<<LOGN) | idx;
  float4 nb = xp[pi], ct = xp[pA];
  float rx=nb.x-ct.x, ry=nb.y-ct.y, rz=nb.z-ct.z;
  float dd = sqrtf(rx*rx+ry*ry+rz*rz);
  float fr[10] = {dd,rx,ry,rz,ct.x,ct.y,ct.z,nb.x,nb.y,nb.z};
  float fx[8];
  #pragma unroll
  for(int c=0;c<8;c++){
    float v = bl1[c];
    #pragma unroll
    for(int j=0;j<10;j++) v += WL1[c*10+j]*fr[j];
    fx[c] = lrelu(v*scL[c]+shL[c]);
  }
  uint4 pk1 = *(const uint4*)(pre1b + (size_t)pi*16);
  float xn[8];
  xn[0]=lrelu(blo(pk1.x)*scP[0]+shP[0]); xn[1]=lrelu(bhi(pk1.x)*scP[1]+shP[1]);
  xn[2]=lrelu(blo(pk1.y)*scP[2]+shP[2]); xn[3]=lrelu(bhi(pk1.y)*scP[3]+shP[3]);
  xn[4]=lrelu(blo(pk1.z)*scP[4]+shP[4]); xn[5]=lrelu(bhi(pk1.z)*scP[5]+shP[5]);
  xn[6]=lrelu(blo(pk1.w)*scP[6]+shP[6]); xn[7]=lrelu(bhi(pk1.w)*scP[7]+shP[7]);

  // XB planes: [h][ (pt*16+k)*16B ] channels h*8..h*8+7 packed bf16
  {
    uint4 d0 = make_uint4(pkbf(xn[0],xn[1]), pkbf(xn[2],xn[3]), pkbf(xn[4],xn[5]), pkbf(xn[6],xn[7]));
    uint4 d1 = make_uint4(pkbf(fx[0],fx[1]), pkbf(fx[2],fx[3]), pkbf(fx[4],fx[5]), pkbf(fx[6],fx[7]));
    *(uint4*)(wb + XB_OFF +        (q*16+l15)*16) = d0;
    *(uint4*)(wb + XB_OFF + 1024 + (q*16+l15)*16) = d1;
  }

  wave_fence();

  // ---- phase B: per point pt: MFMA S^T + register softmax + PV ----
  f32x4 cz = {0.f,0.f,0.f,0.f};
  const char* xrd = wb + XB_OFF + (l15>>3)*1024 + (l15&7)*2;
  #pragma unroll
  for(int pt=0; pt<4; pt++){
    U16 afr; afr.u = make_uint4(0,0,0,0);
    if(q < 2) afr.u = *(const uint4*)(wb + XB_OFF + q*1024 + (pt*16+l15)*16);
    f32x4 cf = __builtin_amdgcn_mfma_f32_16x16x32_bf16(afr.s, bu.s, cz, 0,0,0);
    // softmax over k: this lane holds scores[ch=l15][k=4q+r]
    float mx = fmaxf(fmaxf(cf[0],cf[1]), fmaxf(cf[2],cf[3]));
    mx = fmaxf(mx, __shfl_xor(mx,16));
    mx = fmaxf(mx, __shfl_xor(mx,32));
    float pe0=__expf(cf[0]-mx), pe1=__expf(cf[1]-mx), pe2=__expf(cf[2]-mx), pe3=__expf(cf[3]-mx);
    float ps = pe0+pe1+pe2+pe3;
    ps += __shfl_xor(ps,16);
    ps += __shfl_xor(ps,32);
    // PV: x[l15][4q+r]
    const char* xe = xrd + (pt*16+4*q)*16;
    float acc = pe0*bfu(*(const unsigned short*)(xe))
              + pe1*bfu(*(const unsigned short*)(xe+16))
              + pe2*bfu(*(const unsigned short*)(xe+32))
              + pe3*bfu(*(const unsigned short*)(xe+48));
    acc += __shfl_xor(acc,16);
    acc += __shfl_xor(acc,32);
    float agg = acc*__builtin_amdgcn_rcpf(ps);
    if(q==0) *(float*)(wb + AG_OFF + (pt*16+l15)*4) = agg;
  }

  // lfa2 pre-GN stats from own column fx (phase-A values)
  float l2s[4]={0,0,0,0}, l2q[4]={0,0,0,0};
  #pragma unroll
  for(int c=0;c<8;c++){
    float v = b2[c];
    #pragma unroll
    for(int j=0;j<8;j++) v += W2[c*8+j]*fx[j];
    l2s[c>>1]+=v; l2q[c>>1]+=v*v;
  }

  wave_fence();

  // ---- phase D: point = q, out channel o = l15 (<8) ----
  float m1v = 0.f;
  if(l15 < 8){
    const float4* agp = (const float4*)(wb + AG_OFF + q*64);
    float4 A0=agp[0], A1=agp[1], A2=agp[2], A3=agp[3];
    const float4* wp = (const float4*)(Wm1 + l15*16);
    float4 W0=wp[0], W1_=wp[1], W2_=wp[2], W3=wp[3];
    float v = bm1[l15];
    v += W0.x*A0.x + W0.y*A0.y + W0.z*A0.z + W0.w*A0.w;
    v += W1_.x*A1.x + W1_.y*A1.y + W1_.z*A1.z + W1_.w*A1.w;
    v += W2_.x*A2.x + W2_.y*A2.y + W2_.z*A2.z + W2_.w*A2.w;
    v += W3.x*A3.x + W3.y*A3.y + W3.z*A3.z + W3.w*A3.w;
    m1v = v;
  }
  // pack bf16 pairs and store prem1 (16B/point region, 4B per lane-pair)
  float vpart = __shfl_xor(m1v, 1);
  if(l15 < 8 && (l15&1)==0){
    unsigned u = pkbf(m1v, vpart);
    int pD = (b<<LOGN) | (nbase + q);
    *(unsigned*)(prem1b + (size_t)pD*16 + (l15>>1)*4) = u;
  }

  __syncthreads();
  #pragma unroll
  for(int g=0;g<4;g++){
    float a=wred(l2s[g]), qq=wred(l2q[g]);
    if(lane==0){ atomicAdd(&lst[g*2],a); atomicAdd(&lst[g*2+1],qq); }
  }
  if(l15 < 8){
    atomicAdd(&lst[8+(l15>>1)*2],   m1v);
    atomicAdd(&lst[8+(l15>>1)*2+1], m1v*m1v);
  }
  __syncthreads();
  if(tid<16){
    int half=tid>>3, g=(tid>>1)&3, wsel=tid&1;
    int stage = half? ST_M1 : ST_L2;
    atomicAdd(ws + ((stage*4+b)*4+g)*128 + wsel*64 + (blockIdx.x&63), lst[tid]);
  }
}

// ---------------- K3: att-pool 2, S^T MFMA, register softmax ----------------
__global__ __launch_bounds__(256,6) void k3(
    const int* __restrict__ nidx,
    const float* __restrict__ WL1, const float* __restrict__ bl1,
    const float* __restrict__ W2,  const float* __restrict__ b2,
    const float* __restrict__ Wa2,
    const float* __restrict__ Wm2, const float* __restrict__ bm2,
    float* __restrict__ ws){
  const float* fin = ws + FIN_OFF;
  int b = blockIdx.y;
  int tid = threadIdx.x;
  int w = tid>>6, lane = tid&63, q = lane>>4, l15 = lane&15;
  int nbase = blockIdx.x*16 + w*4;
  int pA = (b<<LOGN) | (nbase + q);

  float scL[8], shL[8], scL2[8], shL2[8], scM[8], shM[8];
  #pragma unroll
  for(int c=0;c<8;c++){
    load_fin(fin, ST_L1, b,c, scL[c], shL[c]);
    load_fin(fin, ST_L2, b,c, scL2[c],shL2[c]);
    load_fin(fin, ST_M1, b,c, scM[c], shM[c]);
  }
  U16 bu; bu.u = make_uint4(0,0,0,0);
  if(q < 2){
    const float* wr = Wa2 + l15*16 + q*8;
    float4 w0 = *(const float4*)(wr);
    float4 w1 = *(const float4*)(wr+4);
    bu.u = make_uint4(pkbf(w0.x,w0.y), pkbf(w0.z,w0.w), pkbf(w1.x,w1.y), pkbf(w1.z,w1.w));
  }

  __shared__ unsigned char SB[4][WV_BYTES];
  __shared__ float lst[8];
  if(tid<8) lst[tid]=0.f;
  char* wb = (char*)SB[w];

  const float4* xp = (const float4*)(ws + XYZP_OFF);
  const char* prem1b = (const char*)(ws + PREM1_OFF);
  float* prem2 = ws + PREM2_OFF;

  // ---- phase A ----
  int idx = nidx[pA*KNB + l15];
  int pi = (b<<LOGN) | idx;
  float4 nb = xp[pi], ct = xp[pA];
  float rx=nb.x-ct.x, ry=nb.y-ct.y, rz=nb.z-ct.z;
  float dd = sqrtf(rx*rx+ry*ry+rz*rz);
  float fr[10] = {dd,rx,ry,rz,ct.x,ct.y,ct.z,nb.x,nb.y,nb.z};
  float fx[8];
  #pragma unroll
  for(int c=0;c<8;c++){
    float v = bl1[c];
    #pragma unroll
    for(int j=0;j<10;j++) v += WL1[c*10+j]*fr[j];
    fx[c] = lrelu(v*scL[c]+shL[c]);
  }
  float fx2[8];
  #pragma unroll
  for(int c=0;c<8;c++){
    float v = b2[c];
    #pragma unroll
    for(int j=0;j<8;j++) v += W2[c*8+j]*fx[j];
    fx2[c] = lrelu(v*scL2[c]+shL2[c]);
  }
  uint4 pm1 = *(const uint4*)(prem1b + (size_t)pi*16);
  float xn[8];
  xn[0]=lrelu(blo(pm1.x)*scM[0]+shM[0]); xn[1]=lrelu(bhi(pm1.x)*scM[1]+shM[1]);
  xn[2]=lrelu(blo(pm1.y)*scM[2]+shM[2]); xn[3]=lrelu(bhi(pm1.y)*scM[3]+shM[3]);
  xn[4]=lrelu(blo(pm1.z)*scM[4]+shM[4]); xn[5]=lrelu(bhi(pm1.z)*scM[5]+shM[5]);
  xn[6]=lrelu(blo(pm1.w)*scM[6]+shM[6]); xn[7]=lrelu(bhi(pm1.w)*scM[7]+shM[7]);

  {
    uint4 d0 = make_uint4(pkbf(xn[0],xn[1]), pkbf(xn[2],xn[3]), pkbf(xn[4],xn[5]), pkbf(xn[6],xn[7]));
    uint4 d1 = make_uint4(pkbf(fx2[0],fx2[1]), pkbf(fx2[2],fx2[3]), pkbf(fx2[4],fx2[5]), pkbf(fx2[6],fx2[7]));
    *(uint4*)(wb + XB_OFF +        (q*16+l15)*16) = d0;
    *(uint4*)(wb + XB_OFF + 1024 + (q*16+l15)*16) = d1;
  }

  wave_fence();

  f32x4 cz = {0.f,0.f,0.f,0.f};
  const char* xrd = wb + XB_OFF + (l15>>3)*1024 + (l15&7)*2;
  #pragma unroll
  for(int pt=0; pt<4; pt++){
    U16 afr; afr.u = make_uint4(0,0,0,0);
    if(q < 2) afr.u = *(const uint4*)(wb + XB_OFF + q*1024 + (pt*16+l15)*16);
    f32x4 cf = __builtin_amdgcn_mfma_f32_16x16x32_bf16(afr.s, bu.s, cz, 0,0,0);
    float mx = fmaxf(fmaxf(cf[0],cf[1]), fmaxf(cf[2],cf[3]));
    mx = fmaxf(mx, __shfl_xor(mx,16));
    mx = fmaxf(mx, __shfl_xor(mx,32));
    float pe0=__expf(cf[0]-mx), pe1=__expf(cf[1]-mx), pe2=__expf(cf[2]-mx), pe3=__expf(cf[3]-mx);
    float ps = pe0+pe1+pe2+pe3;
    ps += __shfl_xor(ps,16);
    ps += __shfl_xor(ps,32);
    const char* xe = xrd + (pt*16+4*q)*16;
    float acc = pe0*bfu(*(const unsigned short*)(xe))
              + pe1*bfu(*(const unsigned short*)(xe+16))
              + pe2*bfu(*(const unsigned short*)(xe+32))
              + pe3*bfu(*(const unsigned short*)(xe+48));
    acc += __shfl_xor(acc,16);
    acc += __shfl_xor(acc,32);
    float agg = acc*__builtin_amdgcn_rcpf(ps);
    if(q==0) *(float*)(wb + AG_OFF + (pt*16+l15)*4) = agg;
  }

  wave_fence();

  // ---- phase D: point = q, out channel o = l15 (16 outs) ----
  float v;
  {
    const float4* agp = (const float4*)(wb + AG_OFF + q*64);
    float4 A0=agp[0], A1=agp[1], A2=agp[2], A3=agp[3];
    const float4* wp = (const float4*)(Wm2 + l15*16);
    float4 W0=wp[0], W1_=wp[1], W2_=wp[2], W3=wp[3];
    v = bm2[l15];
    v += W0.x*A0.x + W0.y*A0.y + W0.z*A0.z + W0.w*A0.w;
    v += W1_.x*A1.x + W1_.y*A1.y + W1_.z*A1.z + W1_.w*A1.w;
    v += W2_.x*A2.x + W2_.y*A2.y + W2_.z*A2.z + W2_.w*A2.w;
    v += W3.x*A3.x + W3.y*A3.y + W3.z*A3.z + W3.w*A3.w;
  }
  int pD = (b<<LOGN) | (nbase + q);
  prem2[(size_t)pD*16 + l15] = v;

  __syncthreads();
  atomicAdd(&lst[(l15>>2)*2],   v);
  atomicAdd(&lst[(l15>>2)*2+1], v*v);
  __syncthreads();
  if(tid<8){
    int g=(tid>>1)&3, wsel=tid&1;
    atomicAdd(ws + ((ST_M2*4+b)*4+g)*128 + wsel*64 + (blockIdx.x&63), lst[tid]);
  }
}

// ---------------- K4: stats of mlp2 output ----------------
__global__ __launch_bounds__(256) void k4(
    const float* __restrict__ Wo,  const float* __restrict__ bo,
    float* __restrict__ ws){
  const float* fin = ws + FIN_OFF;
  int b=blockIdx.y; int n=blockIdx.x*256+threadIdx.x; int p=(b<<LOGN)|n;
  float scM[16], shM[16];
  #pragma unroll
  for(int c=0;c<16;c++) load_fin(fin, ST_M2, b, c, scM[c], shM[c]);
  const float4* pm = (const float4*)(ws + PREM2_OFF) + (size_t)p*4;
  float fa[16];
  #pragma unroll
  for(int i=0;i<4;i++){
    float4 v4 = pm[i];
    fa[i*4+0]=lrelu(v4.x*scM[i*4+0]+shM[i*4+0]);
    fa[i*4+1]=lrelu(v4.y*scM[i*4+1]+shM[i*4+1]);
    fa[i*4+2]=lrelu(v4.z*scM[i*4+2]+shM[i*4+2]);
    fa[i*4+3]=lrelu(v4.w*scM[i*4+3]+shM[i*4+3]);
  }
  float sos[4]={0,0,0,0}, soq[4]={0,0,0,0};
  #pragma unroll
  for(int o=0;o<32;o++){
    float v=bo[o];
    #pragma unroll
    for(int c=0;c<16;c++) v += Wo[o*16+c]*fa[c];
    sos[o>>3]+=v; soq[o>>3]+=v*v;
  }
  __shared__ float lst[8];
  if(threadIdx.x<8) lst[threadIdx.x]=0.f;
  __syncthreads();
  int lane = threadIdx.x & 63;
  #pragma unroll
  for(int g=0;g<4;g++){
    float a=wred(sos[g]), q=wred(soq[g]);
    if(lane==0){ atomicAdd(&lst[g*2],a); atomicAdd(&lst[g*2+1],q); }
  }
  __syncthreads();
  if(threadIdx.x<8){
    int g=(threadIdx.x>>1)&3, w=threadIdx.x&1;
    atomicAdd(ws + ((ST_OUT*4+b)*4+g)*128 + w*64 + (blockIdx.x&63), lst[threadIdx.x]);
  }
}

// ---------------- K5: final out ----------------
__global__ __launch_bounds__(256) void k5(
    const float* __restrict__ feat,
    const float* __restrict__ Wo,  const float* __restrict__ bo,
    const float* __restrict__ Wsk, const float* __restrict__ bsk,
    const float* __restrict__ ws, float* __restrict__ out){
  const float* fin = ws + FIN_OFF;
  int b=blockIdx.y; int n=blockIdx.x*256+threadIdx.x; int p=(b<<LOGN)|n;
  float scM[16], shM[16];
  #pragma unroll
  for(int c=0;c<16;c++) load_fin(fin, ST_M2, b, c, scM[c], shM[c]);
  const float4* pm = (const float4*)(ws + PREM2_OFF) + (size_t)p*4;
  float fa[16];
  #pragma unroll
  for(int i=0;i<4;i++){
    float4 v4 = pm[i];
    fa[i*4+0]=lrelu(v4.x*scM[i*4+0]+shM[i*4+0]);
    fa[i*4+1]=lrelu(v4.y*scM[i*4+1]+shM[i*4+1]);
    fa[i*4+2]=lrelu(v4.z*scM[i*4+2]+shM[i*4+2]);
    fa[i*4+3]=lrelu(v4.w*scM[i*4+3]+shM[i*4+3]);
  }
  float f[8];
  #pragma unroll
  for(int c=0;c<8;c++) f[c]=feat[(b*8+c)*NPTS+n];
  #pragma unroll
  for(int o=0;o<32;o++){
    float to = bo[o];
    #pragma unroll
    for(int c=0;c<16;c++) to += Wo[o*16+c]*fa[c];
    float ts = bsk[o];
    #pragma unroll
    for(int j=0;j<8;j++) ts += Wsk[o*8+j]*f[j];
    float scO, shO, scS, shS;
    load_fin(fin, ST_OUT,  b, o, scO, shO);
    load_fin(fin, ST_SKIP, b, o, scS, shS);
    float v = to*scO+shO + ts*scS+shS;
    out[(b*32+o)*NPTS + n] = lrelu(v);
  }
}

extern "C" void kernel_launch(void* const* d_in, const int* in_sizes, int n_in,
                              void* d_out, int out_size, void* d_ws, size_t ws_size,
                              hipStream_t stream){
  (void)in_sizes; (void)n_in; (void)out_size; (void)ws_size;
  const float* feat=(const float*)d_in[0];
  const float* xyz =(const float*)d_in[1];
  const int*   nidx=(const int*)d_in[2];
  const float* W1  =(const float*)d_in[3];
  const float* b1  =(const float*)d_in[4];
  const float* g1  =(const float*)d_in[5];
  const float* be1 =(const float*)d_in[6];
  const float* WL1 =(const float*)d_in[7];
  const float* bl1 =(const float*)d_in[8];
  const float* gL1 =(const float*)d_in[9];
  const float* beL1=(const float*)d_in[10];
  const float* Wa1 =(const float*)d_in[11];
  const float* Wm1 =(const float*)d_in[12];
  const float* bm1 =(const float*)d_in[13];
  const float* gm1 =(const float*)d_in[14];
  const float* bem1=(const float*)d_in[15];
  const float* W2  =(const float*)d_in[16];
  const float* b2  =(const float*)d_in[17];
  const float* gL2 =(const float*)d_in[18];
  const float* beL2=(const float*)d_in[19];
  const float* Wa2 =(const float*)d_in[20];
  const float* Wm2 =(const float*)d_in[21];
  const float* bm2 =(const float*)d_in[22];
  const float* gm2 =(const float*)d_in[23];
  const float* bem2=(const float*)d_in[24];
  const float* Wo  =(const float*)d_in[25];
  const float* bo  =(const float*)d_in[26];
  const float* go  =(const float*)d_in[27];
  const float* beo =(const float*)d_in[28];
  const float* Wsk =(const float*)d_in[29];
  const float* bsk =(const float*)d_in[30];
  const float* gsk =(const float*)d_in[31];
  const float* besk=(const float*)d_in[32];
  float* ws=(float*)d_ws;
  float* out=(float*)d_out;

  hipMemsetAsync(d_ws, 0, STAT_F*sizeof(float), stream);
  k_pack<<<dim3(1024),dim3(256),0,stream>>>(xyz, ws);
  k1<<<dim3(256,4),dim3(256),0,stream>>>(feat, nidx, W1,b1, Wsk,bsk, WL1,bl1, ws);
  kfA<<<dim3(3),dim3(128),0,stream>>>(ws, g1,be1, gL1,beL1, gsk,besk);
  k2<<<dim3(4096,4),dim3(256),0,stream>>>(nidx, WL1,bl1, Wa1, Wm1,bm1, W2,b2, ws);
  kfB<<<dim3(2),dim3(128),0,stream>>>(ws, gm1,bem1, gL2,beL2);
  k3<<<dim3(4096,4),dim3(256),0,stream>>>(nidx, WL1,bl1, W2,b2, Wa2, Wm2,bm2, ws);
  kfC<<<dim3(1),dim3(128),0,stream>>>(ws, gm2,bem2);
  k4<<<dim3(256,4),dim3(256),0,stream>>>(Wo,bo, ws);
  kfD<<<dim3(1),dim3(128),0,stream>>>(ws, go,beo);
  k5<<<dim3(256,4),dim3(256),0,stream>>>(feat, Wo,bo, Wsk,bsk, ws, out);
}